// Round 1
// baseline (784.626 us; speedup 1.0000x reference)
//
#include <hip/hip_runtime.h>

typedef __bf16 bf16_t;
typedef __bf16 bf16x8 __attribute__((ext_vector_type(8)));
typedef __bf16 bf16x4 __attribute__((ext_vector_type(4)));
typedef float f32x4 __attribute__((ext_vector_type(4)));
typedef unsigned int u32;

#define B_    2
#define T_    2048
#define C_    2048
#define H_    16
#define KV_   4
#define D_    128
#define NT_   4096   // B*T
#define NQKV_ 3072   // H*D + 2*KV*D

__device__ __forceinline__ void gload16(const void* g, void* l) {
  __builtin_amdgcn_global_load_lds((const __attribute__((address_space(1))) u32*)g,
                                   (__attribute__((address_space(3))) u32*)l, 16, 0, 0);
}

// ---------------- fp32 -> bf16 convert (vectorized) ----------------
__global__ __launch_bounds__(256) void k_convert(const float* __restrict__ x,
                                                 bf16_t* __restrict__ y, int n4) {
  int i = blockIdx.x * 256 + threadIdx.x;
  if (i >= n4) return;
  float4 v = ((const float4*)x)[i];
  bf16x4 o;
  o[0] = (bf16_t)v.x; o[1] = (bf16_t)v.y; o[2] = (bf16_t)v.z; o[3] = (bf16_t)v.w;
  ((bf16x4*)y)[i] = o;
}

// ---------------- W[K][N] fp32 -> Wt[N][K] bf16 (LDS tile transpose) ----------------
__global__ __launch_bounds__(256) void k_transpose(const float* __restrict__ W,
                                                   bf16_t* __restrict__ Wt, int K, int N) {
  __shared__ float tile[32][33];
  int n0 = blockIdx.x * 32, k0 = blockIdx.y * 32;
  int tx = threadIdx.x & 31, ty = threadIdx.x >> 5;  // ty in 0..7
#pragma unroll
  for (int r = 0; r < 32; r += 8)
    tile[ty + r][tx] = W[(size_t)(k0 + ty + r) * N + n0 + tx];
  __syncthreads();
#pragma unroll
  for (int r = 0; r < 32; r += 8)
    Wt[(size_t)(n0 + ty + r) * K + k0 + tx] = (bf16_t)tile[tx][ty + r];
}

// ---------------- bias concat [bq|bk|bv] ----------------
__global__ void k_bias(const float* __restrict__ bq, const float* __restrict__ bk,
                       const float* __restrict__ bv, float* __restrict__ o) {
  int i = blockIdx.x * 256 + threadIdx.x;
  if (i < 2048) o[i] = bq[i];
  else if (i < 2560) o[i] = bk[i - 2048];
  else if (i < 3072) o[i] = bv[i - 2560];
}

// ---------------- GEMM: C[M][NTOT] = A[M][2048] @ Wt[NTOT][2048]^T + bias ----------------
// 128x128 tile, BK=32, 256 thr (2x2 waves of 64x64), double-buffered LDS, global_load_lds.
__global__ __launch_bounds__(256) void k_gemm(const bf16_t* __restrict__ A,
                                              const bf16_t* __restrict__ Wt,
                                              const float* __restrict__ bias,
                                              float* __restrict__ Cout, int NTOT) {
  constexpr int K = 2048;
  __shared__ __align__(16) bf16_t As[2][128 * 32];
  __shared__ __align__(16) bf16_t Bs[2][128 * 32];
  const int tid = threadIdx.x;
  const int lane = tid & 63, w = tid >> 6;
  const int c = lane & 15, g = lane >> 4;
  const int wr = w >> 1, wc = w & 1;
  const int m0 = blockIdx.y * 128, n0 = blockIdx.x * 128;
  const int wb = w * 64;

  const f32x4 fz = {0.f, 0.f, 0.f, 0.f};
  f32x4 acc[4][4];
#pragma unroll
  for (int m = 0; m < 4; ++m)
#pragma unroll
    for (int n = 0; n < 4; ++n) acc[m][n] = fz;

  auto stage = [&](int kt, int buf) {
    const int k0 = kt * 32;
#pragma unroll
    for (int i = 0; i < 2; ++i) {
      int lu = i * 256 + wb;   // wave-uniform chunk base
      int lp = lu + lane;      // per-lane chunk: row = lp>>2, 16B-chunk = lp&3
      gload16(A  + (size_t)(m0 + (lp >> 2)) * K + k0 + (lp & 3) * 8, As[buf] + lu * 8);
      gload16(Wt + (size_t)(n0 + (lp >> 2)) * K + k0 + (lp & 3) * 8, Bs[buf] + lu * 8);
    }
  };

  stage(0, 0);
  int cur = 0;
  for (int kt = 0; kt < K / 32; ++kt) {
    __syncthreads();  // buf[cur] loads landed; prev compute on buf[cur^1] done
    if (kt + 1 < K / 32) stage(kt + 1, cur ^ 1);
    bf16x8 a[4], bb[4];
#pragma unroll
    for (int m = 0; m < 4; ++m)
      a[m] = *(const bf16x8*)(As[cur] + (wr * 64 + m * 16 + c) * 32 + g * 8);
#pragma unroll
    for (int n = 0; n < 4; ++n)
      bb[n] = *(const bf16x8*)(Bs[cur] + (wc * 64 + n * 16 + c) * 32 + g * 8);
#pragma unroll
    for (int m = 0; m < 4; ++m)
#pragma unroll
      for (int n = 0; n < 4; ++n)
        acc[m][n] = __builtin_amdgcn_mfma_f32_16x16x32_bf16(a[m], bb[n], acc[m][n], 0, 0, 0);
    cur ^= 1;
  }

#pragma unroll
  for (int n = 0; n < 4; ++n) {
    const int col = n0 + wc * 64 + n * 16 + c;
    const float bn = bias[col];
#pragma unroll
    for (int m = 0; m < 4; ++m) {
      const int row = m0 + wr * 64 + m * 16 + g * 4;
#pragma unroll
      for (int r = 0; r < 4; ++r)
        Cout[(size_t)(row + r) * NTOT + col] = acc[m][n][r] + bn;
    }
  }
}

// ---------------- RMSNorm + RoPE, scatter to Q[b][h][t][d], K[b][kv][t][d], Vt[b][kv][d][t] ----------------
__global__ __launch_bounds__(256) void k_rmsrope(const float* __restrict__ qkv,
                                                 const float* __restrict__ qw,
                                                 const float* __restrict__ kw,
                                                 const float* __restrict__ fc,
                                                 const float* __restrict__ fs,
                                                 bf16_t* __restrict__ Qb,
                                                 bf16_t* __restrict__ Kb,
                                                 bf16_t* __restrict__ Vt) {
  const int bt = blockIdx.x;
  const int u = blockIdx.y * 4 + (threadIdx.x >> 6);  // 0..23: 16 q heads, 4 k heads, 4 v heads
  const int lane = threadIdx.x & 63;                  // pair index i -> d = 2i, 2i+1
  const int b = bt >> 11, t = bt & (T_ - 1);
  int off;
  if (u < 16) off = u * 128;
  else if (u < 20) off = 2048 + (u - 16) * 128;
  else off = 2560 + (u - 20) * 128;
  const float2 ab = *(const float2*)(qkv + (size_t)bt * NQKV_ + off + 2 * lane);
  const float a = ab.x, bv_ = ab.y;
  if (u < 20) {
    float ssq = a * a + bv_ * bv_;
#pragma unroll
    for (int o = 32; o; o >>= 1) ssq += __shfl_xor(ssq, o, 64);
    const float r = rsqrtf(ssq * (1.0f / 128.0f) + 1e-5f);
    const float* wgt = (u < 16) ? qw : kw;
    const float a2 = a * r * wgt[2 * lane];
    const float b2 = bv_ * r * wgt[2 * lane + 1];
    const float cs = fc[t * 64 + lane], sn = fs[t * 64 + lane];
    const float o0 = a2 * cs - b2 * sn;
    const float o1 = a2 * sn + b2 * cs;
    const u32 pk = ((u32)__builtin_bit_cast(unsigned short, (bf16_t)o1) << 16) |
                   (u32)__builtin_bit_cast(unsigned short, (bf16_t)o0);
    if (u < 16)
      *(u32*)(Qb + ((size_t)(b * H_ + u) * T_ + t) * D_ + 2 * lane) = pk;
    else
      *(u32*)(Kb + ((size_t)(b * KV_ + (u - 16)) * T_ + t) * D_ + 2 * lane) = pk;
  } else {
    const int kv = u - 20;
    bf16_t* vp = Vt + (size_t)(b * KV_ + kv) * D_ * T_;
    vp[(size_t)(2 * lane) * T_ + t] = (bf16_t)a;
    vp[(size_t)(2 * lane + 1) * T_ + t] = (bf16_t)bv_;
  }
}

// ---------------- causal GQA flash attention ----------------
// block = (qt, h, b), 4 waves; wave owns 16 q rows; 64-key tiles; online softmax in regs.
__global__ __launch_bounds__(256) void k_attn(const bf16_t* __restrict__ Q,
                                              const bf16_t* __restrict__ K,
                                              const bf16_t* __restrict__ Vt,
                                              bf16_t* __restrict__ Aout) {
  const int qt = blockIdx.x, h = blockIdx.y, b = blockIdx.z;
  const int tid = threadIdx.x, w = tid >> 6, lane = tid & 63;
  const int c = lane & 15, g = lane >> 4;
  const int kv = h >> 2;
  const int q0 = qt * 64;
  __shared__ __align__(16) bf16_t P[4][16][72];  // per-wave P scratch, padded (stride 144B)

  const bf16_t* Qp = Q + ((size_t)(b * H_ + h) * T_ + q0 + w * 16 + c) * D_;
  const bf16_t* Kp = K + (size_t)(b * KV_ + kv) * T_ * D_;
  const bf16_t* Vp = Vt + (size_t)(b * KV_ + kv) * D_ * T_;

  bf16x8 qf[4];
#pragma unroll
  for (int ks = 0; ks < 4; ++ks) qf[ks] = *(const bf16x8*)(Qp + ks * 32 + g * 8);

  const f32x4 fz = {0.f, 0.f, 0.f, 0.f};
  f32x4 o[8];
#pragma unroll
  for (int d = 0; d < 8; ++d) o[d] = fz;
  float mr[4], lr[4];
#pragma unroll
  for (int r = 0; r < 4; ++r) { mr[r] = -__builtin_inff(); lr[r] = 0.f; }
  const float scale = 0.08838834764831845f;  // 1/sqrt(128)

  for (int kt = 0; kt <= qt; ++kt) {
    const int k0 = kt * 64;
    // S = Q K^T (16 x 64 per wave)
    f32x4 s[4];
#pragma unroll
    for (int jf = 0; jf < 4; ++jf) {
      f32x4 sj = fz;
      const bf16_t* kp = Kp + (size_t)(k0 + jf * 16 + c) * D_ + g * 8;
#pragma unroll
      for (int ks = 0; ks < 4; ++ks) {
        bf16x8 kf = *(const bf16x8*)(kp + ks * 32);
        sj = __builtin_amdgcn_mfma_f32_16x16x32_bf16(qf[ks], kf, sj, 0, 0, 0);
      }
      s[jf] = sj;
    }
    // scale + causal mask (only the diagonal tile is partial)
    if (kt == qt) {
#pragma unroll
      for (int jf = 0; jf < 4; ++jf) {
        const int key = k0 + jf * 16 + c;
#pragma unroll
        for (int r = 0; r < 4; ++r) {
          const int qr = q0 + w * 16 + g * 4 + r;
          s[jf][r] = (key <= qr) ? s[jf][r] * scale : -1e30f;
        }
      }
    } else {
#pragma unroll
      for (int jf = 0; jf < 4; ++jf)
#pragma unroll
        for (int r = 0; r < 4; ++r) s[jf][r] *= scale;
    }
    // online softmax: row r lives in (lane>>4)*4+r across the 16-lane col group
    float tm[4];
#pragma unroll
    for (int r = 0; r < 4; ++r) {
      tm[r] = fmaxf(fmaxf(s[0][r], s[1][r]), fmaxf(s[2][r], s[3][r]));
      tm[r] = fmaxf(tm[r], __shfl_xor(tm[r], 1, 64));
      tm[r] = fmaxf(tm[r], __shfl_xor(tm[r], 2, 64));
      tm[r] = fmaxf(tm[r], __shfl_xor(tm[r], 4, 64));
      tm[r] = fmaxf(tm[r], __shfl_xor(tm[r], 8, 64));
    }
    float al[4], rs[4];
#pragma unroll
    for (int r = 0; r < 4; ++r) {
      const float nm = fmaxf(mr[r], tm[r]);
      al[r] = __expf(mr[r] - nm);
      mr[r] = nm;
      rs[r] = 0.f;
    }
#pragma unroll
    for (int jf = 0; jf < 4; ++jf)
#pragma unroll
      for (int r = 0; r < 4; ++r) {
        const float p = __expf(s[jf][r] - mr[r]);
        s[jf][r] = p;
        rs[r] += p;
      }
#pragma unroll
    for (int r = 0; r < 4; ++r) {
      rs[r] += __shfl_xor(rs[r], 1, 64);
      rs[r] += __shfl_xor(rs[r], 2, 64);
      rs[r] += __shfl_xor(rs[r], 4, 64);
      rs[r] += __shfl_xor(rs[r], 8, 64);
      lr[r] = lr[r] * al[r] + rs[r];
    }
#pragma unroll
    for (int d = 0; d < 8; ++d)
#pragma unroll
      for (int r = 0; r < 4; ++r) o[d][r] *= al[r];
    // P -> per-wave LDS (re-layout D-frag -> A-frag), then PV
#pragma unroll
    for (int jf = 0; jf < 4; ++jf)
#pragma unroll
      for (int r = 0; r < 4; ++r)
        P[w][g * 4 + r][jf * 16 + c] = (bf16_t)s[jf][r];
#pragma unroll
    for (int ks2 = 0; ks2 < 2; ++ks2) {
      const bf16x8 pa = *(const bf16x8*)&P[w][c][ks2 * 32 + g * 8];
#pragma unroll
      for (int d = 0; d < 8; ++d) {
        const bf16x8 vf = *(const bf16x8*)(Vp + (size_t)(d * 16 + c) * T_ + k0 + ks2 * 32 + g * 8);
        o[d] = __builtin_amdgcn_mfma_f32_16x16x32_bf16(pa, vf, o[d], 0, 0, 0);
      }
    }
  }
  float inv[4];
#pragma unroll
  for (int r = 0; r < 4; ++r) inv[r] = 1.0f / lr[r];
#pragma unroll
  for (int d = 0; d < 8; ++d)
#pragma unroll
    for (int r = 0; r < 4; ++r)
      Aout[(size_t)(b * T_ + q0 + w * 16 + g * 4 + r) * C_ + h * D_ + d * 16 + c] =
          (bf16_t)(o[d][r] * inv[r]);
}

extern "C" void kernel_launch(void* const* d_in, const int* in_sizes, int n_in,
                              void* d_out, int out_size, void* d_ws, size_t ws_size,
                              hipStream_t stream) {
  const float* x  = (const float*)d_in[0];
  const float* Wq = (const float*)d_in[1];
  const float* bq = (const float*)d_in[2];
  const float* Wk = (const float*)d_in[3];
  const float* bk = (const float*)d_in[4];
  const float* Wv = (const float*)d_in[5];
  const float* bv = (const float*)d_in[6];
  const float* Wo = (const float*)d_in[7];
  const float* bo = (const float*)d_in[8];
  const float* qw = (const float*)d_in[9];
  const float* kw = (const float*)d_in[10];
  const float* fc = (const float*)d_in[11];
  const float* fs = (const float*)d_in[12];
  float* out = (float*)d_out;

  char* p = (char*)d_ws;
  bf16_t* xb   = (bf16_t*)p; p += (size_t)NT_ * C_ * 2;        // 16.8 MB (reused as attn out)
  bf16_t* Wqkv = (bf16_t*)p; p += (size_t)NQKV_ * C_ * 2;      // 12.6 MB  [N][K] bf16
  bf16_t* Wot  = (bf16_t*)p; p += (size_t)C_ * C_ * 2;         //  8.4 MB  [N][K] bf16
  float*  qkv  = (float*)p;  p += (size_t)NT_ * NQKV_ * 4;     // 50.3 MB
  bf16_t* Qb   = (bf16_t*)p; p += (size_t)B_ * H_ * T_ * D_ * 2;   // 16.8 MB
  bf16_t* Kb   = (bf16_t*)p; p += (size_t)B_ * KV_ * T_ * D_ * 2;  //  4.2 MB
  bf16_t* Vt   = (bf16_t*)p; p += (size_t)B_ * KV_ * T_ * D_ * 2;  //  4.2 MB [b][kv][d][T]
  float*  bqkv = (float*)p;  p += NQKV_ * 4;
  bf16_t* attn = xb;  // xb dead after GEMM1

  k_convert<<<NT_ * C_ / 4 / 256, 256, 0, stream>>>(x, xb, NT_ * C_ / 4);
  k_transpose<<<dim3(64, 64), 256, 0, stream>>>(Wq, Wqkv, 2048, 2048);
  k_transpose<<<dim3(16, 64), 256, 0, stream>>>(Wk, Wqkv + (size_t)2048 * 2048, 2048, 512);
  k_transpose<<<dim3(16, 64), 256, 0, stream>>>(Wv, Wqkv + (size_t)2560 * 2048, 2048, 512);
  k_transpose<<<dim3(64, 64), 256, 0, stream>>>(Wo, Wot, 2048, 2048);
  k_bias<<<12, 256, 0, stream>>>(bq, bk, bv, bqkv);
  k_gemm<<<dim3(NQKV_ / 128, NT_ / 128), 256, 0, stream>>>(xb, Wqkv, bqkv, qkv, NQKV_);
  k_rmsrope<<<dim3(NT_, 6), 256, 0, stream>>>(qkv, qw, kw, fc, fs, Qb, Kb, Vt);
  k_attn<<<dim3(T_ / 64, H_, B_), 256, 0, stream>>>(Qb, Kb, Vt, attn);
  k_gemm<<<dim3(C_ / 128, NT_ / 128), 256, 0, stream>>>(attn, Wot, bo, out, C_);
}

// Round 2
// 513.201 us; speedup vs baseline: 1.5289x; 1.5289x over previous
//
#include <hip/hip_runtime.h>

typedef __bf16 bf16_t;
typedef __bf16 bf16x8 __attribute__((ext_vector_type(8)));
typedef __bf16 bf16x4 __attribute__((ext_vector_type(4)));
typedef float f32x4 __attribute__((ext_vector_type(4)));
typedef unsigned int u32;

#define B_    2
#define T_    2048
#define C_    2048
#define H_    16
#define KV_   4
#define D_    128
#define NT_   4096   // B*T
#define NQKV_ 3072   // H*D + 2*KV*D

__device__ __forceinline__ void gload16(const void* g, void* l) {
  __builtin_amdgcn_global_load_lds((const __attribute__((address_space(1))) u32*)g,
                                   (__attribute__((address_space(3))) u32*)l, 16, 0, 0);
}

// ---------------- fp32 -> bf16 convert (vectorized) ----------------
__global__ __launch_bounds__(256) void k_convert(const float* __restrict__ x,
                                                 bf16_t* __restrict__ y, int n4) {
  int i = blockIdx.x * 256 + threadIdx.x;
  if (i >= n4) return;
  float4 v = ((const float4*)x)[i];
  bf16x4 o;
  o[0] = (bf16_t)v.x; o[1] = (bf16_t)v.y; o[2] = (bf16_t)v.z; o[3] = (bf16_t)v.w;
  ((bf16x4*)y)[i] = o;
}

// ---------------- W[K][N] fp32 -> Wt[N][K] bf16 (LDS tile transpose) ----------------
__global__ __launch_bounds__(256) void k_transpose(const float* __restrict__ W,
                                                   bf16_t* __restrict__ Wt, int K, int N) {
  __shared__ float tile[32][33];
  int n0 = blockIdx.x * 32, k0 = blockIdx.y * 32;
  int tx = threadIdx.x & 31, ty = threadIdx.x >> 5;  // ty in 0..7
#pragma unroll
  for (int r = 0; r < 32; r += 8)
    tile[ty + r][tx] = W[(size_t)(k0 + ty + r) * N + n0 + tx];
  __syncthreads();
#pragma unroll
  for (int r = 0; r < 32; r += 8)
    Wt[(size_t)(n0 + ty + r) * K + k0 + tx] = (bf16_t)tile[tx][ty + r];
}

// ---------------- bias concat [bq|bk|bv] ----------------
__global__ void k_bias(const float* __restrict__ bq, const float* __restrict__ bk,
                       const float* __restrict__ bv, float* __restrict__ o) {
  int i = blockIdx.x * 256 + threadIdx.x;
  if (i < 2048) o[i] = bq[i];
  else if (i < 2560) o[i] = bk[i - 2048];
  else if (i < 3072) o[i] = bv[i - 2560];
}

// ---------------- GEMM: C[M][NTOT] = A[M][2048] @ Wt[NTOT][2048]^T + bias ----------------
// 128x128 tile, BK=32, 256 thr (2x2 waves of 64x64), double-buffered LDS, global_load_lds.
__global__ __launch_bounds__(256) void k_gemm(const bf16_t* __restrict__ A,
                                              const bf16_t* __restrict__ Wt,
                                              const float* __restrict__ bias,
                                              float* __restrict__ Cout, int NTOT) {
  constexpr int K = 2048;
  __shared__ __align__(16) bf16_t As[2][128 * 32];
  __shared__ __align__(16) bf16_t Bs[2][128 * 32];
  const int tid = threadIdx.x;
  const int lane = tid & 63, w = tid >> 6;
  const int c = lane & 15, g = lane >> 4;
  const int wr = w >> 1, wc = w & 1;
  const int m0 = blockIdx.y * 128, n0 = blockIdx.x * 128;
  const int wb = w * 64;

  const f32x4 fz = {0.f, 0.f, 0.f, 0.f};
  f32x4 acc[4][4];
#pragma unroll
  for (int m = 0; m < 4; ++m)
#pragma unroll
    for (int n = 0; n < 4; ++n) acc[m][n] = fz;

  auto stage = [&](int kt, int buf) {
    const int k0 = kt * 32;
#pragma unroll
    for (int i = 0; i < 2; ++i) {
      int lu = i * 256 + wb;   // wave-uniform chunk base
      int lp = lu + lane;      // per-lane chunk: row = lp>>2, 16B-chunk = lp&3
      gload16(A  + (size_t)(m0 + (lp >> 2)) * K + k0 + (lp & 3) * 8, As[buf] + lu * 8);
      gload16(Wt + (size_t)(n0 + (lp >> 2)) * K + k0 + (lp & 3) * 8, Bs[buf] + lu * 8);
    }
  };

  stage(0, 0);
  int cur = 0;
  for (int kt = 0; kt < K / 32; ++kt) {
    __syncthreads();  // buf[cur] loads landed; prev compute on buf[cur^1] done
    if (kt + 1 < K / 32) stage(kt + 1, cur ^ 1);
    bf16x8 a[4], bb[4];
#pragma unroll
    for (int m = 0; m < 4; ++m)
      a[m] = *(const bf16x8*)(As[cur] + (wr * 64 + m * 16 + c) * 32 + g * 8);
#pragma unroll
    for (int n = 0; n < 4; ++n)
      bb[n] = *(const bf16x8*)(Bs[cur] + (wc * 64 + n * 16 + c) * 32 + g * 8);
#pragma unroll
    for (int m = 0; m < 4; ++m)
#pragma unroll
      for (int n = 0; n < 4; ++n)
        acc[m][n] = __builtin_amdgcn_mfma_f32_16x16x32_bf16(a[m], bb[n], acc[m][n], 0, 0, 0);
    cur ^= 1;
  }

#pragma unroll
  for (int n = 0; n < 4; ++n) {
    const int col = n0 + wc * 64 + n * 16 + c;
    const float bn = bias[col];
#pragma unroll
    for (int m = 0; m < 4; ++m) {
      const int row = m0 + wr * 64 + m * 16 + g * 4;
#pragma unroll
      for (int r = 0; r < 4; ++r)
        Cout[(size_t)(row + r) * NTOT + col] = acc[m][n][r] + bn;
    }
  }
}

// ---------------- RMSNorm + RoPE, scatter to Q[b][h][t][d], K[b][kv][t][d], Vt[b][kv][d][t] ----------------
__global__ __launch_bounds__(256) void k_rmsrope(const float* __restrict__ qkv,
                                                 const float* __restrict__ qw,
                                                 const float* __restrict__ kw,
                                                 const float* __restrict__ fc,
                                                 const float* __restrict__ fs,
                                                 bf16_t* __restrict__ Qb,
                                                 bf16_t* __restrict__ Kb,
                                                 bf16_t* __restrict__ Vt) {
  const int bt = blockIdx.x;
  const int u = blockIdx.y * 4 + (threadIdx.x >> 6);  // 0..23: 16 q heads, 4 k heads, 4 v heads
  const int lane = threadIdx.x & 63;                  // pair index i -> d = 2i, 2i+1
  const int b = bt >> 11, t = bt & (T_ - 1);
  int off;
  if (u < 16) off = u * 128;
  else if (u < 20) off = 2048 + (u - 16) * 128;
  else off = 2560 + (u - 20) * 128;
  const float2 ab = *(const float2*)(qkv + (size_t)bt * NQKV_ + off + 2 * lane);
  const float a = ab.x, bv_ = ab.y;
  if (u < 20) {
    float ssq = a * a + bv_ * bv_;
#pragma unroll
    for (int o = 32; o; o >>= 1) ssq += __shfl_xor(ssq, o, 64);
    const float r = rsqrtf(ssq * (1.0f / 128.0f) + 1e-5f);
    const float* wgt = (u < 16) ? qw : kw;
    const float a2 = a * r * wgt[2 * lane];
    const float b2 = bv_ * r * wgt[2 * lane + 1];
    const float cs = fc[t * 64 + lane], sn = fs[t * 64 + lane];
    const float o0 = a2 * cs - b2 * sn;
    const float o1 = a2 * sn + b2 * cs;
    const u32 pk = ((u32)__builtin_bit_cast(unsigned short, (bf16_t)o1) << 16) |
                   (u32)__builtin_bit_cast(unsigned short, (bf16_t)o0);
    if (u < 16)
      *(u32*)(Qb + ((size_t)(b * H_ + u) * T_ + t) * D_ + 2 * lane) = pk;
    else
      *(u32*)(Kb + ((size_t)(b * KV_ + (u - 16)) * T_ + t) * D_ + 2 * lane) = pk;
  } else {
    const int kv = u - 20;
    bf16_t* vp = Vt + (size_t)(b * KV_ + kv) * D_ * T_;
    vp[(size_t)(2 * lane) * T_ + t] = (bf16_t)a;
    vp[(size_t)(2 * lane + 1) * T_ + t] = (bf16_t)bv_;
  }
}

// ---------------- causal GQA flash attention v2 ----------------
// Block = (pair pi, h, b): processes q-tiles qt=pi and qt=31-pi (64 rows each) -> every
// block does exactly 33 key-tile iterations (perfect balance; 512 blocks = 2/CU).
// K/V tiles staged cooperatively in LDS (double-buffered, XOR-swizzled), reg-prefetch
// of the next tile issued right after the barrier so L2 latency hides under compute.
__global__ __launch_bounds__(256) void k_attn(const bf16_t* __restrict__ Q,
                                              const bf16_t* __restrict__ K,
                                              const bf16_t* __restrict__ Vt,
                                              bf16_t* __restrict__ Aout) {
  const int pi = blockIdx.x, h = blockIdx.y, b = blockIdx.z;
  const int tid = threadIdx.x, w = tid >> 6, lane = tid & 63;
  const int c = lane & 15, g = lane >> 4;
  const int kv = h >> 2;

  __shared__ __align__(16) bf16_t Ks[2][64 * 128];   // [key][d], swizzled
  __shared__ __align__(16) bf16_t Vs[2][128 * 64];   // [d][key], swizzled
  __shared__ __align__(16) bf16_t P[4][16][72];      // per-wave P scratch

  const bf16_t* Kp = K + (size_t)(b * KV_ + kv) * T_ * D_;
  const bf16_t* Vp = Vt + (size_t)(b * KV_ + kv) * D_ * T_;
  const float scale = 0.08838834764831845f;  // 1/sqrt(128)
  const f32x4 fz = {0.f, 0.f, 0.f, 0.f};

  int4 kreg[4], vreg[4];  // staging registers (32 VGPRs)
  auto stage_load = [&](int k0) {
#pragma unroll
    for (int i = 0; i < 4; ++i) {
      const int ck = tid + i * 256;
      kreg[i] = *(const int4*)(Kp + (size_t)(k0 + (ck >> 4)) * D_ + (ck & 15) * 8);
      vreg[i] = *(const int4*)(Vp + (size_t)(ck >> 3) * T_ + k0 + (ck & 7) * 8);
    }
  };
  auto stage_write = [&](int buf) {
#pragma unroll
    for (int i = 0; i < 4; ++i) {
      const int ck = tid + i * 256;
      // K row = ck>>4 (256B rows), V row = ck>>3 (128B rows); XOR-swizzle bits 4-6 by row&7
      *(int4*)((char*)(Ks[buf]) + (ck >> 4) * 256 + (((ck & 15) * 16) ^ (((ck >> 4) & 7) << 4))) = kreg[i];
      *(int4*)((char*)(Vs[buf]) + (ck >> 3) * 128 + (((ck & 7) * 16) ^ (((ck >> 3) & 7) << 4))) = vreg[i];
    }
  };

#pragma unroll 1
  for (int ph = 0; ph < 2; ++ph) {
    const int qt = (ph == 0) ? pi : 31 - pi;
    const int q0 = qt * 64;
    const int nkt = qt + 1;

    const bf16_t* Qp = Q + ((size_t)(b * H_ + h) * T_ + q0 + w * 16 + c) * D_;
    bf16x8 qf[4];
#pragma unroll
    for (int ks = 0; ks < 4; ++ks) qf[ks] = *(const bf16x8*)(Qp + ks * 32 + g * 8);

    f32x4 o[8];
#pragma unroll
    for (int d = 0; d < 8; ++d) o[d] = fz;
    float mr[4], lr[4];
#pragma unroll
    for (int r = 0; r < 4; ++r) { mr[r] = -__builtin_inff(); lr[r] = 0.f; }

    stage_load(0);
    if (ph == 1) __syncthreads();  // all waves done reading phase-0 LDS
    stage_write(0);
    int cur = 0;

#pragma unroll 1
    for (int kt = 0; kt < nkt; ++kt) {
      __syncthreads();  // LDS[cur] writes visible; nobody reads LDS[cur^1] after this
      if (kt + 1 < nkt) stage_load((kt + 1) * 64);  // prefetch: latency hides under compute
      const int k0 = kt * 64;
      const char* Kc = (const char*)(Ks[cur]);
      const char* Vc = (const char*)(Vs[cur]);
      const int sw = (c & 7) << 4;

      // S = Q K^T (16 x 64 per wave)
      f32x4 s[4];
#pragma unroll
      for (int jf = 0; jf < 4; ++jf) {
        f32x4 sj = fz;
#pragma unroll
        for (int ks = 0; ks < 4; ++ks) {
          bf16x8 kf = *(const bf16x8*)(Kc + (jf * 16 + c) * 256 + (((ks * 4 + g) * 16) ^ sw));
          sj = __builtin_amdgcn_mfma_f32_16x16x32_bf16(qf[ks], kf, sj, 0, 0, 0);
        }
        s[jf] = sj;
      }
      // scale + causal mask (only the diagonal tile is partial)
      if (kt == qt) {
#pragma unroll
        for (int jf = 0; jf < 4; ++jf) {
          const int key = k0 + jf * 16 + c;
#pragma unroll
          for (int r = 0; r < 4; ++r) {
            const int qr = q0 + w * 16 + g * 4 + r;
            s[jf][r] = (key <= qr) ? s[jf][r] * scale : -1e30f;
          }
        }
      } else {
#pragma unroll
        for (int jf = 0; jf < 4; ++jf)
#pragma unroll
          for (int r = 0; r < 4; ++r) s[jf][r] *= scale;
      }
      // online softmax
      float tm[4];
#pragma unroll
      for (int r = 0; r < 4; ++r) {
        tm[r] = fmaxf(fmaxf(s[0][r], s[1][r]), fmaxf(s[2][r], s[3][r]));
        tm[r] = fmaxf(tm[r], __shfl_xor(tm[r], 1, 64));
        tm[r] = fmaxf(tm[r], __shfl_xor(tm[r], 2, 64));
        tm[r] = fmaxf(tm[r], __shfl_xor(tm[r], 4, 64));
        tm[r] = fmaxf(tm[r], __shfl_xor(tm[r], 8, 64));
      }
      float al[4], rs[4];
#pragma unroll
      for (int r = 0; r < 4; ++r) {
        const float nm = fmaxf(mr[r], tm[r]);
        al[r] = __expf(mr[r] - nm);
        mr[r] = nm;
        rs[r] = 0.f;
      }
#pragma unroll
      for (int jf = 0; jf < 4; ++jf)
#pragma unroll
        for (int r = 0; r < 4; ++r) {
          const float p = __expf(s[jf][r] - mr[r]);
          s[jf][r] = p;
          rs[r] += p;
        }
#pragma unroll
      for (int r = 0; r < 4; ++r) {
        rs[r] += __shfl_xor(rs[r], 1, 64);
        rs[r] += __shfl_xor(rs[r], 2, 64);
        rs[r] += __shfl_xor(rs[r], 4, 64);
        rs[r] += __shfl_xor(rs[r], 8, 64);
        lr[r] = lr[r] * al[r] + rs[r];
      }
#pragma unroll
      for (int d = 0; d < 8; ++d)
#pragma unroll
        for (int r = 0; r < 4; ++r) o[d][r] *= al[r];
      // P -> per-wave LDS (D-frag -> A-frag re-layout), then PV from swizzled Vs
#pragma unroll
      for (int jf = 0; jf < 4; ++jf)
#pragma unroll
        for (int r = 0; r < 4; ++r)
          P[w][g * 4 + r][jf * 16 + c] = (bf16_t)s[jf][r];
#pragma unroll
      for (int ks2 = 0; ks2 < 2; ++ks2) {
        const bf16x8 pa = *(const bf16x8*)&P[w][c][ks2 * 32 + g * 8];
#pragma unroll
        for (int d = 0; d < 8; ++d) {
          const bf16x8 vf = *(const bf16x8*)(Vc + (d * 16 + c) * 128 + (((ks2 * 4 + g) * 16) ^ sw));
          o[d] = __builtin_amdgcn_mfma_f32_16x16x32_bf16(pa, vf, o[d], 0, 0, 0);
        }
      }
      if (kt + 1 < nkt) stage_write(cur ^ 1);  // write next tile into the idle buffer
      cur ^= 1;
    }

    float inv[4];
#pragma unroll
    for (int r = 0; r < 4; ++r) inv[r] = 1.0f / lr[r];
#pragma unroll
    for (int d = 0; d < 8; ++d)
#pragma unroll
      for (int r = 0; r < 4; ++r)
        Aout[(size_t)(b * T_ + q0 + w * 16 + g * 4 + r) * C_ + h * D_ + d * 16 + c] =
            (bf16_t)(o[d][r] * inv[r]);
  }
}

extern "C" void kernel_launch(void* const* d_in, const int* in_sizes, int n_in,
                              void* d_out, int out_size, void* d_ws, size_t ws_size,
                              hipStream_t stream) {
  const float* x  = (const float*)d_in[0];
  const float* Wq = (const float*)d_in[1];
  const float* bq = (const float*)d_in[2];
  const float* Wk = (const float*)d_in[3];
  const float* bk = (const float*)d_in[4];
  const float* Wv = (const float*)d_in[5];
  const float* bv = (const float*)d_in[6];
  const float* Wo = (const float*)d_in[7];
  const float* bo = (const float*)d_in[8];
  const float* qw = (const float*)d_in[9];
  const float* kw = (const float*)d_in[10];
  const float* fc = (const float*)d_in[11];
  const float* fs = (const float*)d_in[12];
  float* out = (float*)d_out;

  char* p = (char*)d_ws;
  bf16_t* xb   = (bf16_t*)p; p += (size_t)NT_ * C_ * 2;        // 16.8 MB (reused as attn out)
  bf16_t* Wqkv = (bf16_t*)p; p += (size_t)NQKV_ * C_ * 2;      // 12.6 MB  [N][K] bf16
  bf16_t* Wot  = (bf16_t*)p; p += (size_t)C_ * C_ * 2;         //  8.4 MB  [N][K] bf16
  float*  qkv  = (float*)p;  p += (size_t)NT_ * NQKV_ * 4;     // 50.3 MB
  bf16_t* Qb   = (bf16_t*)p; p += (size_t)B_ * H_ * T_ * D_ * 2;   // 16.8 MB
  bf16_t* Kb   = (bf16_t*)p; p += (size_t)B_ * KV_ * T_ * D_ * 2;  //  4.2 MB
  bf16_t* Vt   = (bf16_t*)p; p += (size_t)B_ * KV_ * T_ * D_ * 2;  //  4.2 MB [b][kv][d][T]
  float*  bqkv = (float*)p;  p += NQKV_ * 4;
  bf16_t* attn = xb;  // xb dead after GEMM1

  k_convert<<<NT_ * C_ / 4 / 256, 256, 0, stream>>>(x, xb, NT_ * C_ / 4);
  k_transpose<<<dim3(64, 64), 256, 0, stream>>>(Wq, Wqkv, 2048, 2048);
  k_transpose<<<dim3(16, 64), 256, 0, stream>>>(Wk, Wqkv + (size_t)2048 * 2048, 2048, 512);
  k_transpose<<<dim3(16, 64), 256, 0, stream>>>(Wv, Wqkv + (size_t)2560 * 2048, 2048, 512);
  k_transpose<<<dim3(64, 64), 256, 0, stream>>>(Wo, Wot, 2048, 2048);
  k_bias<<<12, 256, 0, stream>>>(bq, bk, bv, bqkv);
  k_gemm<<<dim3(NQKV_ / 128, NT_ / 128), 256, 0, stream>>>(xb, Wqkv, bqkv, qkv, NQKV_);
  k_rmsrope<<<dim3(NT_, 6), 256, 0, stream>>>(qkv, qw, kw, fc, fs, Qb, Kb, Vt);
  k_attn<<<dim3(16, H_, B_), 256, 0, stream>>>(Qb, Kb, Vt, attn);
  k_gemm<<<dim3(C_ / 128, NT_ / 128), 256, 0, stream>>>(attn, Wot, bo, out, C_);
}

// Round 3
// 429.902 us; speedup vs baseline: 1.8251x; 1.1938x over previous
//
#include <hip/hip_runtime.h>

typedef __bf16 bf16_t;
typedef __bf16 bf16x8 __attribute__((ext_vector_type(8)));
typedef __bf16 bf16x4 __attribute__((ext_vector_type(4)));
typedef float f32x4 __attribute__((ext_vector_type(4)));
typedef unsigned int u32;

#define B_    2
#define T_    2048
#define C_    2048
#define H_    16
#define KV_   4
#define D_    128
#define NT_   4096   // B*T
#define NQKV_ 3072   // H*D + 2*KV*D

__device__ __forceinline__ void gload16(const void* g, void* l) {
  __builtin_amdgcn_global_load_lds((const __attribute__((address_space(1))) u32*)g,
                                   (__attribute__((address_space(3))) u32*)l, 16, 0, 0);
}

// ---------------- fp32 -> bf16 convert (vectorized) ----------------
__global__ __launch_bounds__(256) void k_convert(const float* __restrict__ x,
                                                 bf16_t* __restrict__ y, int n4) {
  int i = blockIdx.x * 256 + threadIdx.x;
  if (i >= n4) return;
  float4 v = ((const float4*)x)[i];
  bf16x4 o;
  o[0] = (bf16_t)v.x; o[1] = (bf16_t)v.y; o[2] = (bf16_t)v.z; o[3] = (bf16_t)v.w;
  ((bf16x4*)y)[i] = o;
}

// ---------------- W[K][N] fp32 -> Wt[N][K] bf16 (LDS tile transpose) ----------------
__global__ __launch_bounds__(256) void k_transpose(const float* __restrict__ W,
                                                   bf16_t* __restrict__ Wt, int K, int N) {
  __shared__ float tile[32][33];
  int n0 = blockIdx.x * 32, k0 = blockIdx.y * 32;
  int tx = threadIdx.x & 31, ty = threadIdx.x >> 5;  // ty in 0..7
#pragma unroll
  for (int r = 0; r < 32; r += 8)
    tile[ty + r][tx] = W[(size_t)(k0 + ty + r) * N + n0 + tx];
  __syncthreads();
#pragma unroll
  for (int r = 0; r < 32; r += 8)
    Wt[(size_t)(n0 + ty + r) * K + k0 + tx] = (bf16_t)tile[tx][ty + r];
}

// ---------------- bias concat [bq|bk|bv] ----------------
__global__ void k_bias(const float* __restrict__ bq, const float* __restrict__ bk,
                       const float* __restrict__ bv, float* __restrict__ o) {
  int i = blockIdx.x * 256 + threadIdx.x;
  if (i < 2048) o[i] = bq[i];
  else if (i < 2560) o[i] = bk[i - 2048];
  else if (i < 3072) o[i] = bv[i - 2560];
}

// ---------------- GEMM: C[M][NTOT] = A[M][2048] @ Wt[NTOT][2048]^T + bias ----------------
// 128x128 tile, BK=32, 256 thr (2x2 waves of 64x64), double-buffered LDS, global_load_lds.
__global__ __launch_bounds__(256) void k_gemm(const bf16_t* __restrict__ A,
                                              const bf16_t* __restrict__ Wt,
                                              const float* __restrict__ bias,
                                              float* __restrict__ Cout, int NTOT) {
  constexpr int K = 2048;
  __shared__ __align__(16) bf16_t As[2][128 * 32];
  __shared__ __align__(16) bf16_t Bs[2][128 * 32];
  const int tid = threadIdx.x;
  const int lane = tid & 63, w = tid >> 6;
  const int c = lane & 15, g = lane >> 4;
  const int wr = w >> 1, wc = w & 1;
  const int m0 = blockIdx.y * 128, n0 = blockIdx.x * 128;
  const int wb = w * 64;

  const f32x4 fz = {0.f, 0.f, 0.f, 0.f};
  f32x4 acc[4][4];
#pragma unroll
  for (int m = 0; m < 4; ++m)
#pragma unroll
    for (int n = 0; n < 4; ++n) acc[m][n] = fz;

  auto stage = [&](int kt, int buf) {
    const int k0 = kt * 32;
#pragma unroll
    for (int i = 0; i < 2; ++i) {
      int lu = i * 256 + wb;   // wave-uniform chunk base
      int lp = lu + lane;      // per-lane chunk: row = lp>>2, 16B-chunk = lp&3
      gload16(A  + (size_t)(m0 + (lp >> 2)) * K + k0 + (lp & 3) * 8, As[buf] + lu * 8);
      gload16(Wt + (size_t)(n0 + (lp >> 2)) * K + k0 + (lp & 3) * 8, Bs[buf] + lu * 8);
    }
  };

  stage(0, 0);
  int cur = 0;
  for (int kt = 0; kt < K / 32; ++kt) {
    __syncthreads();  // buf[cur] loads landed; prev compute on buf[cur^1] done
    if (kt + 1 < K / 32) stage(kt + 1, cur ^ 1);
    bf16x8 a[4], bb[4];
#pragma unroll
    for (int m = 0; m < 4; ++m)
      a[m] = *(const bf16x8*)(As[cur] + (wr * 64 + m * 16 + c) * 32 + g * 8);
#pragma unroll
    for (int n = 0; n < 4; ++n)
      bb[n] = *(const bf16x8*)(Bs[cur] + (wc * 64 + n * 16 + c) * 32 + g * 8);
#pragma unroll
    for (int m = 0; m < 4; ++m)
#pragma unroll
      for (int n = 0; n < 4; ++n)
        acc[m][n] = __builtin_amdgcn_mfma_f32_16x16x32_bf16(a[m], bb[n], acc[m][n], 0, 0, 0);
    cur ^= 1;
  }

#pragma unroll
  for (int n = 0; n < 4; ++n) {
    const int col = n0 + wc * 64 + n * 16 + c;
    const float bn = bias[col];
#pragma unroll
    for (int m = 0; m < 4; ++m) {
      const int row = m0 + wr * 64 + m * 16 + g * 4;
#pragma unroll
      for (int r = 0; r < 4; ++r)
        Cout[(size_t)(row + r) * NTOT + col] = acc[m][n][r] + bn;
    }
  }
}

// ---------------- RMSNorm + RoPE, scatter to Q[b][h][t][d], K[b][kv][t][d], Vt[b][kv][d][t] ----------------
__global__ __launch_bounds__(256) void k_rmsrope(const float* __restrict__ qkv,
                                                 const float* __restrict__ qw,
                                                 const float* __restrict__ kw,
                                                 const float* __restrict__ fc,
                                                 const float* __restrict__ fs,
                                                 bf16_t* __restrict__ Qb,
                                                 bf16_t* __restrict__ Kb,
                                                 bf16_t* __restrict__ Vt) {
  const int bt = blockIdx.x;
  const int u = blockIdx.y * 4 + (threadIdx.x >> 6);  // 0..23: 16 q heads, 4 k heads, 4 v heads
  const int lane = threadIdx.x & 63;                  // pair index i -> d = 2i, 2i+1
  const int b = bt >> 11, t = bt & (T_ - 1);
  int off;
  if (u < 16) off = u * 128;
  else if (u < 20) off = 2048 + (u - 16) * 128;
  else off = 2560 + (u - 20) * 128;
  const float2 ab = *(const float2*)(qkv + (size_t)bt * NQKV_ + off + 2 * lane);
  const float a = ab.x, bv_ = ab.y;
  if (u < 20) {
    float ssq = a * a + bv_ * bv_;
#pragma unroll
    for (int o = 32; o; o >>= 1) ssq += __shfl_xor(ssq, o, 64);
    const float r = rsqrtf(ssq * (1.0f / 128.0f) + 1e-5f);
    const float* wgt = (u < 16) ? qw : kw;
    const float a2 = a * r * wgt[2 * lane];
    const float b2 = bv_ * r * wgt[2 * lane + 1];
    const float cs = fc[t * 64 + lane], sn = fs[t * 64 + lane];
    const float o0 = a2 * cs - b2 * sn;
    const float o1 = a2 * sn + b2 * cs;
    const u32 pk = ((u32)__builtin_bit_cast(unsigned short, (bf16_t)o1) << 16) |
                   (u32)__builtin_bit_cast(unsigned short, (bf16_t)o0);
    if (u < 16)
      *(u32*)(Qb + ((size_t)(b * H_ + u) * T_ + t) * D_ + 2 * lane) = pk;
    else
      *(u32*)(Kb + ((size_t)(b * KV_ + (u - 16)) * T_ + t) * D_ + 2 * lane) = pk;
  } else {
    const int kv = u - 20;
    bf16_t* vp = Vt + (size_t)(b * KV_ + kv) * D_ * T_;
    vp[(size_t)(2 * lane) * T_ + t] = (bf16_t)a;
    vp[(size_t)(2 * lane + 1) * T_ + t] = (bf16_t)bv_;
  }
}

// ---------------- causal GQA flash attention v3 ----------------
// Block = (pair pi, h, b): q-tiles pi and 31-pi -> exactly 33 key-tile iters per block.
// K/V staged via global_load_lds (zero staging VGPRs, no scratch) into XOR-swizzled
// LDS: linear LDS dest + inverse-swizzled per-lane GLOBAL source (involution), so the
// swizzled ds_read side is unchanged. Double-buffered; next-tile loads issued right
// after the barrier so their latency hides under the current tile's compute.
__global__ __launch_bounds__(256) void k_attn(const bf16_t* __restrict__ Q,
                                              const bf16_t* __restrict__ K,
                                              const bf16_t* __restrict__ Vt,
                                              bf16_t* __restrict__ Aout) {
  const int pi = blockIdx.x, h = blockIdx.y, b = blockIdx.z;
  const int tid = threadIdx.x, w = tid >> 6, lane = tid & 63;
  const int c = lane & 15, g = lane >> 4;
  const int kv = h >> 2;

  __shared__ __align__(16) bf16_t Ks[2][64 * 128];   // [key][d], swizzled (256B rows)
  __shared__ __align__(16) bf16_t Vs[2][128 * 64];   // [d][key], swizzled (128B rows)
  __shared__ __align__(16) bf16_t P[4][16][72];      // per-wave P scratch

  const bf16_t* Kp = K + (size_t)(b * KV_ + kv) * T_ * D_;
  const bf16_t* Vp = Vt + (size_t)(b * KV_ + kv) * D_ * T_;
  const float scale = 0.08838834764831845f;  // 1/sqrt(128)
  const f32x4 fz = {0.f, 0.f, 0.f, 0.f};

  // Per-lane inverse-swizzled source chunk coords (constant across tiles).
  // K tile: 64 rows x 16 chunks of 16B. LDS linear chunk ck -> global (row, chunk^(row&7)).
  // V tile: 128 rows x 8 chunks of 16B.  LDS linear chunk ck -> global (row, chunk^(row&7)).
  int krow[4], kcol[4], vrow[4], vcol[4];
#pragma unroll
  for (int i = 0; i < 4; ++i) {
    const int ck = i * 256 + w * 64 + lane;
    krow[i] = ck >> 4;
    kcol[i] = (((ck & 15) ^ ((ck >> 4) & 7)) * 8);
    vrow[i] = ck >> 3;
    vcol[i] = (((ck & 7) ^ ((ck >> 3) & 7)) * 8);
  }

  auto stage = [&](int k0, int buf) {
#pragma unroll
    for (int i = 0; i < 4; ++i) {
      const int lu = (i * 256 + w * 64) * 8;  // wave-uniform LDS elem base (lane*16B auto)
      gload16(Kp + (size_t)(k0 + krow[i]) * D_ + kcol[i], Ks[buf] + lu);
      gload16(Vp + (size_t)vrow[i] * T_ + k0 + vcol[i], Vs[buf] + lu);
    }
  };

#pragma unroll 1
  for (int ph = 0; ph < 2; ++ph) {
    const int qt = (ph == 0) ? pi : 31 - pi;
    const int q0 = qt * 64;
    const int nkt = qt + 1;

    const bf16_t* Qp = Q + ((size_t)(b * H_ + h) * T_ + q0 + w * 16 + c) * D_;
    bf16x8 qf[4];
#pragma unroll
    for (int ks = 0; ks < 4; ++ks) qf[ks] = *(const bf16x8*)(Qp + ks * 32 + g * 8);

    f32x4 o[8];
#pragma unroll
    for (int d = 0; d < 8; ++d) o[d] = fz;
    float mr[4], lr[4];
#pragma unroll
    for (int r = 0; r < 4; ++r) { mr[r] = -__builtin_inff(); lr[r] = 0.f; }

    if (ph == 1) __syncthreads();  // all waves done reading phase-0 LDS
    stage(0, 0);
    int cur = 0;

#pragma unroll 1
    for (int kt = 0; kt < nkt; ++kt) {
      __syncthreads();  // drains vmcnt: buf[cur] staged; nobody still reads buf[cur^1]
      if (kt + 1 < nkt) stage((kt + 1) * 64, cur ^ 1);  // in flight across this compute
      const int k0 = kt * 64;
      const char* Kc = (const char*)(Ks[cur]);
      const char* Vc = (const char*)(Vs[cur]);
      const int sw = (c & 7) << 4;

      // S = Q K^T (16 x 64 per wave)
      f32x4 s[4];
#pragma unroll
      for (int jf = 0; jf < 4; ++jf) {
        f32x4 sj = fz;
#pragma unroll
        for (int ks = 0; ks < 4; ++ks) {
          bf16x8 kf = *(const bf16x8*)(Kc + (jf * 16 + c) * 256 + (((ks * 4 + g) * 16) ^ sw));
          sj = __builtin_amdgcn_mfma_f32_16x16x32_bf16(qf[ks], kf, sj, 0, 0, 0);
        }
        s[jf] = sj;
      }
      // scale + causal mask (only the diagonal tile is partial)
      if (kt == qt) {
#pragma unroll
        for (int jf = 0; jf < 4; ++jf) {
          const int key = k0 + jf * 16 + c;
#pragma unroll
          for (int r = 0; r < 4; ++r) {
            const int qr = q0 + w * 16 + g * 4 + r;
            s[jf][r] = (key <= qr) ? s[jf][r] * scale : -1e30f;
          }
        }
      } else {
#pragma unroll
        for (int jf = 0; jf < 4; ++jf)
#pragma unroll
          for (int r = 0; r < 4; ++r) s[jf][r] *= scale;
      }
      // online softmax
      float tm[4];
#pragma unroll
      for (int r = 0; r < 4; ++r) {
        tm[r] = fmaxf(fmaxf(s[0][r], s[1][r]), fmaxf(s[2][r], s[3][r]));
        tm[r] = fmaxf(tm[r], __shfl_xor(tm[r], 1, 64));
        tm[r] = fmaxf(tm[r], __shfl_xor(tm[r], 2, 64));
        tm[r] = fmaxf(tm[r], __shfl_xor(tm[r], 4, 64));
        tm[r] = fmaxf(tm[r], __shfl_xor(tm[r], 8, 64));
      }
      float al[4], rs[4];
#pragma unroll
      for (int r = 0; r < 4; ++r) {
        const float nm = fmaxf(mr[r], tm[r]);
        al[r] = __expf(mr[r] - nm);
        mr[r] = nm;
        rs[r] = 0.f;
      }
#pragma unroll
      for (int jf = 0; jf < 4; ++jf)
#pragma unroll
        for (int r = 0; r < 4; ++r) {
          const float p = __expf(s[jf][r] - mr[r]);
          s[jf][r] = p;
          rs[r] += p;
        }
#pragma unroll
      for (int r = 0; r < 4; ++r) {
        rs[r] += __shfl_xor(rs[r], 1, 64);
        rs[r] += __shfl_xor(rs[r], 2, 64);
        rs[r] += __shfl_xor(rs[r], 4, 64);
        rs[r] += __shfl_xor(rs[r], 8, 64);
        lr[r] = lr[r] * al[r] + rs[r];
      }
#pragma unroll
      for (int d = 0; d < 8; ++d)
#pragma unroll
        for (int r = 0; r < 4; ++r) o[d][r] *= al[r];
      // P -> per-wave LDS (D-frag -> A-frag re-layout), then PV from swizzled Vs
#pragma unroll
      for (int jf = 0; jf < 4; ++jf)
#pragma unroll
        for (int r = 0; r < 4; ++r)
          P[w][g * 4 + r][jf * 16 + c] = (bf16_t)s[jf][r];
#pragma unroll
      for (int ks2 = 0; ks2 < 2; ++ks2) {
        const bf16x8 pa = *(const bf16x8*)&P[w][c][ks2 * 32 + g * 8];
#pragma unroll
        for (int d = 0; d < 8; ++d) {
          const bf16x8 vf = *(const bf16x8*)(Vc + (d * 16 + c) * 128 + (((ks2 * 4 + g) * 16) ^ sw));
          o[d] = __builtin_amdgcn_mfma_f32_16x16x32_bf16(pa, vf, o[d], 0, 0, 0);
        }
      }
      cur ^= 1;
    }

    float inv[4];
#pragma unroll
    for (int r = 0; r < 4; ++r) inv[r] = 1.0f / lr[r];
#pragma unroll
    for (int d = 0; d < 8; ++d)
#pragma unroll
      for (int r = 0; r < 4; ++r)
        Aout[(size_t)(b * T_ + q0 + w * 16 + g * 4 + r) * C_ + h * D_ + d * 16 + c] =
            (bf16_t)(o[d][r] * inv[r]);
  }
}

extern "C" void kernel_launch(void* const* d_in, const int* in_sizes, int n_in,
                              void* d_out, int out_size, void* d_ws, size_t ws_size,
                              hipStream_t stream) {
  const float* x  = (const float*)d_in[0];
  const float* Wq = (const float*)d_in[1];
  const float* bq = (const float*)d_in[2];
  const float* Wk = (const float*)d_in[3];
  const float* bk = (const float*)d_in[4];
  const float* Wv = (const float*)d_in[5];
  const float* bv = (const float*)d_in[6];
  const float* Wo = (const float*)d_in[7];
  const float* bo = (const float*)d_in[8];
  const float* qw = (const float*)d_in[9];
  const float* kw = (const float*)d_in[10];
  const float* fc = (const float*)d_in[11];
  const float* fs = (const float*)d_in[12];
  float* out = (float*)d_out;

  char* p = (char*)d_ws;
  bf16_t* xb   = (bf16_t*)p; p += (size_t)NT_ * C_ * 2;        // 16.8 MB (reused as attn out)
  bf16_t* Wqkv = (bf16_t*)p; p += (size_t)NQKV_ * C_ * 2;      // 12.6 MB  [N][K] bf16
  bf16_t* Wot  = (bf16_t*)p; p += (size_t)C_ * C_ * 2;         //  8.4 MB  [N][K] bf16
  float*  qkv  = (float*)p;  p += (size_t)NT_ * NQKV_ * 4;     // 50.3 MB
  bf16_t* Qb   = (bf16_t*)p; p += (size_t)B_ * H_ * T_ * D_ * 2;   // 16.8 MB
  bf16_t* Kb   = (bf16_t*)p; p += (size_t)B_ * KV_ * T_ * D_ * 2;  //  4.2 MB
  bf16_t* Vt   = (bf16_t*)p; p += (size_t)B_ * KV_ * T_ * D_ * 2;  //  4.2 MB [b][kv][d][T]
  float*  bqkv = (float*)p;  p += NQKV_ * 4;
  bf16_t* attn = xb;  // xb dead after GEMM1

  k_convert<<<NT_ * C_ / 4 / 256, 256, 0, stream>>>(x, xb, NT_ * C_ / 4);
  k_transpose<<<dim3(64, 64), 256, 0, stream>>>(Wq, Wqkv, 2048, 2048);
  k_transpose<<<dim3(16, 64), 256, 0, stream>>>(Wk, Wqkv + (size_t)2048 * 2048, 2048, 512);
  k_transpose<<<dim3(16, 64), 256, 0, stream>>>(Wv, Wqkv + (size_t)2560 * 2048, 2048, 512);
  k_transpose<<<dim3(64, 64), 256, 0, stream>>>(Wo, Wot, 2048, 2048);
  k_bias<<<12, 256, 0, stream>>>(bq, bk, bv, bqkv);
  k_gemm<<<dim3(NQKV_ / 128, NT_ / 128), 256, 0, stream>>>(xb, Wqkv, bqkv, qkv, NQKV_);
  k_rmsrope<<<dim3(NT_, 6), 256, 0, stream>>>(qkv, qw, kw, fc, fs, Qb, Kb, Vt);
  k_attn<<<dim3(16, H_, B_), 256, 0, stream>>>(Qb, Kb, Vt, attn);
  k_gemm<<<dim3(C_ / 128, NT_ / 128), 256, 0, stream>>>(attn, Wot, bo, out, C_);
}

// Round 4
// 384.941 us; speedup vs baseline: 2.0383x; 1.1168x over previous
//
#include <hip/hip_runtime.h>

typedef __bf16 bf16_t;
typedef __bf16 bf16x8 __attribute__((ext_vector_type(8)));
typedef __bf16 bf16x4 __attribute__((ext_vector_type(4)));
typedef float f32x4 __attribute__((ext_vector_type(4)));
typedef unsigned int u32;

#define B_    2
#define T_    2048
#define C_    2048
#define H_    16
#define KV_   4
#define D_    128
#define NT_   4096   // B*T
#define NQKV_ 3072   // H*D + 2*KV*D

__device__ __forceinline__ void gload16(const void* g, void* l) {
  __builtin_amdgcn_global_load_lds((const __attribute__((address_space(1))) u32*)g,
                                   (__attribute__((address_space(3))) u32*)l, 16, 0, 0);
}

// ---------------- fp32 -> bf16 convert (vectorized) ----------------
__global__ __launch_bounds__(256) void k_convert(const float* __restrict__ x,
                                                 bf16_t* __restrict__ y, int n4) {
  int i = blockIdx.x * 256 + threadIdx.x;
  if (i >= n4) return;
  float4 v = ((const float4*)x)[i];
  bf16x4 o;
  o[0] = (bf16_t)v.x; o[1] = (bf16_t)v.y; o[2] = (bf16_t)v.z; o[3] = (bf16_t)v.w;
  ((bf16x4*)y)[i] = o;
}

// ---------------- W[K][N] fp32 -> Wt[N][K] bf16 (LDS tile transpose) ----------------
__global__ __launch_bounds__(256) void k_transpose(const float* __restrict__ W,
                                                   bf16_t* __restrict__ Wt, int K, int N) {
  __shared__ float tile[32][33];
  int n0 = blockIdx.x * 32, k0 = blockIdx.y * 32;
  int tx = threadIdx.x & 31, ty = threadIdx.x >> 5;  // ty in 0..7
#pragma unroll
  for (int r = 0; r < 32; r += 8)
    tile[ty + r][tx] = W[(size_t)(k0 + ty + r) * N + n0 + tx];
  __syncthreads();
#pragma unroll
  for (int r = 0; r < 32; r += 8)
    Wt[(size_t)(n0 + ty + r) * K + k0 + tx] = (bf16_t)tile[tx][ty + r];
}

// ---------------- bias concat [bq|bk|bv] ----------------
__global__ void k_bias(const float* __restrict__ bq, const float* __restrict__ bk,
                       const float* __restrict__ bv, float* __restrict__ o) {
  int i = blockIdx.x * 256 + threadIdx.x;
  if (i < 2048) o[i] = bq[i];
  else if (i < 2560) o[i] = bk[i - 2048];
  else if (i < 3072) o[i] = bv[i - 2560];
}

// ---------------- GEMM v2: phase-pipelined 256x128 tile ----------------
// C[M][NTOT] = A[M][2048] @ Wt[NTOT][2048]^T + bias.  512 thr = 8 waves (4Mx2N),
// per-wave 64x64 (acc[4][4]).  BK=64, ring-3 LDS (144 KB), prefetch distance 2
// K-tiles via global_load_lds, counted vmcnt(6) once per K-tile (never 0), raw
// s_barrier (no vmcnt drain), 2 phases/K-tile with 16-MFMA clusters + setprio,
// XOR-swizzled LDS (chunk ^= row&7): bank-conflict-free b128 reads; staging uses
// the inverse-permuted GLOBAL source so LDS dest stays linear (gload_lds rule).
__global__ __launch_bounds__(512, 2) void k_gemm(const bf16_t* __restrict__ A,
                                                 const bf16_t* __restrict__ Wt,
                                                 const float* __restrict__ bias,
                                                 float* __restrict__ Cout, int NTOT) {
  constexpr int K = 2048;
  constexpr int NK = K / 64;             // 32 K-tiles
  __shared__ __align__(16) bf16_t Asr[3][256 * 64];   // 96 KB
  __shared__ __align__(16) bf16_t Bsr[3][128 * 64];   // 48 KB
  const int tid = threadIdx.x;
  const int lane = tid & 63, w = tid >> 6;
  const int c = lane & 15, g = lane >> 4;
  const int wr = w >> 1, wc = w & 1;
  const int m0 = blockIdx.y * 256, n0 = blockIdx.x * 128;

  // constant per-lane staging coords: LDS chunk ck -> global (row, chunk^(row&7))
  int arow[4], asc[4], brow[2], bsc[2];
#pragma unroll
  for (int i = 0; i < 4; ++i) {
    const int ck = i * 512 + w * 64 + lane;
    arow[i] = ck >> 3; asc[i] = ((ck & 7) ^ ((ck >> 3) & 7)) * 8;
  }
#pragma unroll
  for (int j = 0; j < 2; ++j) {
    const int ck = j * 512 + w * 64 + lane;
    brow[j] = ck >> 3; bsc[j] = ((ck & 7) ^ ((ck >> 3) & 7)) * 8;
  }
  // constant fragment-read offsets (elements): row*64 + ((ks*4+g)^(row&7))*8
  const int swz0 = ((0 * 4 + g) ^ (c & 7)) * 8;
  const int swz1 = ((1 * 4 + g) ^ (c & 7)) * 8;
  const int aro = (wr * 64 + c) * 64;    // + m*1024
  const int bro = (wc * 64 + c) * 64;    // + n*1024

  const f32x4 fz = {0.f, 0.f, 0.f, 0.f};
  f32x4 acc[4][4];
#pragma unroll
  for (int m = 0; m < 4; ++m)
#pragma unroll
    for (int n = 0; n < 4; ++n) acc[m][n] = fz;

  auto stageA2 = [&](int ts, int sl, int i0) {
    const int k0 = ts * 64;
#pragma unroll
    for (int i = i0; i < i0 + 2; ++i)
      gload16(A + (size_t)(m0 + arow[i]) * K + k0 + asc[i],
              Asr[sl] + (i * 512 + w * 64) * 8);
  };
  auto stageB1 = [&](int ts, int sl, int j) {
    const int k0 = ts * 64;
    gload16(Wt + (size_t)(n0 + brow[j]) * K + k0 + bsc[j],
            Bsr[sl] + (j * 512 + w * 64) * 8);
  };

  // prologue: tiles 0,1 -> slots 0,1 (12 loads); wait tile 0 (all but last 6)
  stageA2(0, 0, 0); stageA2(0, 0, 2); stageB1(0, 0, 0); stageB1(0, 0, 1);
  stageA2(1, 1, 0); stageA2(1, 1, 2); stageB1(1, 1, 0); stageB1(1, 1, 1);
  asm volatile("s_waitcnt vmcnt(6)" ::: "memory");
  __builtin_amdgcn_s_barrier();

  int slot = 0;
#pragma unroll 1
  for (int t = 0; t < NK; ++t) {
    const int sl2 = (slot >= 1) ? slot - 1 : 2;          // (t+2) % 3
    const int ts = (t + 2 < NK) ? t + 2 : NK - 1;        // clamp: garbage into dead slot
    const bf16_t* Ap = Asr[slot];
    const bf16_t* Bp = Bsr[slot];

    // ---- phase A: quadrant n=0,1 ----
    bf16x8 af[4][2], b01[2][2];
#pragma unroll
    for (int m = 0; m < 4; ++m) {
      af[m][0] = *(const bf16x8*)(Ap + aro + m * 1024 + swz0);
      af[m][1] = *(const bf16x8*)(Ap + aro + m * 1024 + swz1);
    }
#pragma unroll
    for (int n = 0; n < 2; ++n) {
      b01[n][0] = *(const bf16x8*)(Bp + bro + n * 1024 + swz0);
      b01[n][1] = *(const bf16x8*)(Bp + bro + n * 1024 + swz1);
    }
    stageA2(ts, sl2, 0); stageB1(ts, sl2, 0);
    __builtin_amdgcn_s_barrier();
    asm volatile("s_waitcnt lgkmcnt(0)" ::: "memory");
    __builtin_amdgcn_sched_barrier(0);
    __builtin_amdgcn_s_setprio(1);
#pragma unroll
    for (int m = 0; m < 4; ++m)
#pragma unroll
      for (int n = 0; n < 2; ++n) {
        acc[m][n] = __builtin_amdgcn_mfma_f32_16x16x32_bf16(af[m][0], b01[n][0], acc[m][n], 0, 0, 0);
        acc[m][n] = __builtin_amdgcn_mfma_f32_16x16x32_bf16(af[m][1], b01[n][1], acc[m][n], 0, 0, 0);
      }
    __builtin_amdgcn_s_setprio(0);
    __builtin_amdgcn_s_barrier();

    // ---- phase B: quadrant n=2,3 (reuse af) ----
    bf16x8 b23[2][2];
#pragma unroll
    for (int n = 0; n < 2; ++n) {
      b23[n][0] = *(const bf16x8*)(Bp + bro + (n + 2) * 1024 + swz0);
      b23[n][1] = *(const bf16x8*)(Bp + bro + (n + 2) * 1024 + swz1);
    }
    stageA2(ts, sl2, 2); stageB1(ts, sl2, 1);
    __builtin_amdgcn_s_barrier();
    asm volatile("s_waitcnt lgkmcnt(0)" ::: "memory");
    __builtin_amdgcn_sched_barrier(0);
    __builtin_amdgcn_s_setprio(1);
#pragma unroll
    for (int m = 0; m < 4; ++m)
#pragma unroll
      for (int n = 0; n < 2; ++n) {
        acc[m][n + 2] = __builtin_amdgcn_mfma_f32_16x16x32_bf16(af[m][0], b23[n][0], acc[m][n + 2], 0, 0, 0);
        acc[m][n + 2] = __builtin_amdgcn_mfma_f32_16x16x32_bf16(af[m][1], b23[n][1], acc[m][n + 2], 0, 0, 0);
      }
    __builtin_amdgcn_s_setprio(0);
    asm volatile("s_waitcnt vmcnt(6)" ::: "memory");   // tile t+1 fully landed
    __builtin_amdgcn_s_barrier();
    __builtin_amdgcn_sched_barrier(0);
    slot = (slot == 2) ? 0 : slot + 1;
  }

#pragma unroll
  for (int n = 0; n < 4; ++n) {
    const int col = n0 + wc * 64 + n * 16 + c;
    const float bn = bias[col];
#pragma unroll
    for (int m = 0; m < 4; ++m) {
      const int row = m0 + wr * 64 + m * 16 + g * 4;
#pragma unroll
      for (int r = 0; r < 4; ++r)
        Cout[(size_t)(row + r) * NTOT + col] = acc[m][n][r] + bn;
    }
  }
}

// ---------------- RMSNorm + RoPE, scatter to Q[b][h][t][d], K[b][kv][t][d], Vt[b][kv][d][t] ----------------
__global__ __launch_bounds__(256) void k_rmsrope(const float* __restrict__ qkv,
                                                 const float* __restrict__ qw,
                                                 const float* __restrict__ kw,
                                                 const float* __restrict__ fc,
                                                 const float* __restrict__ fs,
                                                 bf16_t* __restrict__ Qb,
                                                 bf16_t* __restrict__ Kb,
                                                 bf16_t* __restrict__ Vt) {
  const int bt = blockIdx.x;
  const int u = blockIdx.y * 4 + (threadIdx.x >> 6);  // 0..23: 16 q heads, 4 k heads, 4 v heads
  const int lane = threadIdx.x & 63;                  // pair index i -> d = 2i, 2i+1
  const int b = bt >> 11, t = bt & (T_ - 1);
  int off;
  if (u < 16) off = u * 128;
  else if (u < 20) off = 2048 + (u - 16) * 128;
  else off = 2560 + (u - 20) * 128;
  const float2 ab = *(const float2*)(qkv + (size_t)bt * NQKV_ + off + 2 * lane);
  const float a = ab.x, bv_ = ab.y;
  if (u < 20) {
    float ssq = a * a + bv_ * bv_;
#pragma unroll
    for (int o = 32; o; o >>= 1) ssq += __shfl_xor(ssq, o, 64);
    const float r = rsqrtf(ssq * (1.0f / 128.0f) + 1e-5f);
    const float* wgt = (u < 16) ? qw : kw;
    const float a2 = a * r * wgt[2 * lane];
    const float b2 = bv_ * r * wgt[2 * lane + 1];
    const float cs = fc[t * 64 + lane], sn = fs[t * 64 + lane];
    const float o0 = a2 * cs - b2 * sn;
    const float o1 = a2 * sn + b2 * cs;
    const u32 pk = ((u32)__builtin_bit_cast(unsigned short, (bf16_t)o1) << 16) |
                   (u32)__builtin_bit_cast(unsigned short, (bf16_t)o0);
    if (u < 16)
      *(u32*)(Qb + ((size_t)(b * H_ + u) * T_ + t) * D_ + 2 * lane) = pk;
    else
      *(u32*)(Kb + ((size_t)(b * KV_ + (u - 16)) * T_ + t) * D_ + 2 * lane) = pk;
  } else {
    const int kv = u - 20;
    bf16_t* vp = Vt + (size_t)(b * KV_ + kv) * D_ * T_;
    vp[(size_t)(2 * lane) * T_ + t] = (bf16_t)a;
    vp[(size_t)(2 * lane + 1) * T_ + t] = (bf16_t)bv_;
  }
}

// ---------------- causal GQA flash attention v3 ----------------
__global__ __launch_bounds__(256) void k_attn(const bf16_t* __restrict__ Q,
                                              const bf16_t* __restrict__ K,
                                              const bf16_t* __restrict__ Vt,
                                              bf16_t* __restrict__ Aout) {
  const int pi = blockIdx.x, h = blockIdx.y, b = blockIdx.z;
  const int tid = threadIdx.x, w = tid >> 6, lane = tid & 63;
  const int c = lane & 15, g = lane >> 4;
  const int kv = h >> 2;

  __shared__ __align__(16) bf16_t Ks[2][64 * 128];   // [key][d], swizzled (256B rows)
  __shared__ __align__(16) bf16_t Vs[2][128 * 64];   // [d][key], swizzled (128B rows)
  __shared__ __align__(16) bf16_t P[4][16][72];      // per-wave P scratch

  const bf16_t* Kp = K + (size_t)(b * KV_ + kv) * T_ * D_;
  const bf16_t* Vp = Vt + (size_t)(b * KV_ + kv) * D_ * T_;
  const float scale = 0.08838834764831845f;  // 1/sqrt(128)
  const f32x4 fz = {0.f, 0.f, 0.f, 0.f};

  int krow[4], kcol[4], vrow[4], vcol[4];
#pragma unroll
  for (int i = 0; i < 4; ++i) {
    const int ck = i * 256 + w * 64 + lane;
    krow[i] = ck >> 4;
    kcol[i] = (((ck & 15) ^ ((ck >> 4) & 7)) * 8);
    vrow[i] = ck >> 3;
    vcol[i] = (((ck & 7) ^ ((ck >> 3) & 7)) * 8);
  }

  auto stage = [&](int k0, int buf) {
#pragma unroll
    for (int i = 0; i < 4; ++i) {
      const int lu = (i * 256 + w * 64) * 8;  // wave-uniform LDS elem base (lane*16B auto)
      gload16(Kp + (size_t)(k0 + krow[i]) * D_ + kcol[i], Ks[buf] + lu);
      gload16(Vp + (size_t)vrow[i] * T_ + k0 + vcol[i], Vs[buf] + lu);
    }
  };

#pragma unroll 1
  for (int ph = 0; ph < 2; ++ph) {
    const int qt = (ph == 0) ? pi : 31 - pi;
    const int q0 = qt * 64;
    const int nkt = qt + 1;

    const bf16_t* Qp = Q + ((size_t)(b * H_ + h) * T_ + q0 + w * 16 + c) * D_;
    bf16x8 qf[4];
#pragma unroll
    for (int ks = 0; ks < 4; ++ks) qf[ks] = *(const bf16x8*)(Qp + ks * 32 + g * 8);

    f32x4 o[8];
#pragma unroll
    for (int d = 0; d < 8; ++d) o[d] = fz;
    float mr[4], lr[4];
#pragma unroll
    for (int r = 0; r < 4; ++r) { mr[r] = -__builtin_inff(); lr[r] = 0.f; }

    if (ph == 1) __syncthreads();  // all waves done reading phase-0 LDS
    stage(0, 0);
    int cur = 0;

#pragma unroll 1
    for (int kt = 0; kt < nkt; ++kt) {
      __syncthreads();  // drains vmcnt: buf[cur] staged; nobody still reads buf[cur^1]
      if (kt + 1 < nkt) stage((kt + 1) * 64, cur ^ 1);  // in flight across this compute
      const int k0 = kt * 64;
      const char* Kc = (const char*)(Ks[cur]);
      const char* Vc = (const char*)(Vs[cur]);
      const int sw = (c & 7) << 4;

      // S = Q K^T (16 x 64 per wave)
      f32x4 s[4];
#pragma unroll
      for (int jf = 0; jf < 4; ++jf) {
        f32x4 sj = fz;
#pragma unroll
        for (int ks = 0; ks < 4; ++ks) {
          bf16x8 kf = *(const bf16x8*)(Kc + (jf * 16 + c) * 256 + (((ks * 4 + g) * 16) ^ sw));
          sj = __builtin_amdgcn_mfma_f32_16x16x32_bf16(qf[ks], kf, sj, 0, 0, 0);
        }
        s[jf] = sj;
      }
      // scale + causal mask (only the diagonal tile is partial)
      if (kt == qt) {
#pragma unroll
        for (int jf = 0; jf < 4; ++jf) {
          const int key = k0 + jf * 16 + c;
#pragma unroll
          for (int r = 0; r < 4; ++r) {
            const int qr = q0 + w * 16 + g * 4 + r;
            s[jf][r] = (key <= qr) ? s[jf][r] * scale : -1e30f;
          }
        }
      } else {
#pragma unroll
        for (int jf = 0; jf < 4; ++jf)
#pragma unroll
          for (int r = 0; r < 4; ++r) s[jf][r] *= scale;
      }
      // online softmax
      float tm[4];
#pragma unroll
      for (int r = 0; r < 4; ++r) {
        tm[r] = fmaxf(fmaxf(s[0][r], s[1][r]), fmaxf(s[2][r], s[3][r]));
        tm[r] = fmaxf(tm[r], __shfl_xor(tm[r], 1, 64));
        tm[r] = fmaxf(tm[r], __shfl_xor(tm[r], 2, 64));
        tm[r] = fmaxf(tm[r], __shfl_xor(tm[r], 4, 64));
        tm[r] = fmaxf(tm[r], __shfl_xor(tm[r], 8, 64));
      }
      float al[4], rs[4];
#pragma unroll
      for (int r = 0; r < 4; ++r) {
        const float nm = fmaxf(mr[r], tm[r]);
        al[r] = __expf(mr[r] - nm);
        mr[r] = nm;
        rs[r] = 0.f;
      }
#pragma unroll
      for (int jf = 0; jf < 4; ++jf)
#pragma unroll
        for (int r = 0; r < 4; ++r) {
          const float p = __expf(s[jf][r] - mr[r]);
          s[jf][r] = p;
          rs[r] += p;
        }
#pragma unroll
      for (int r = 0; r < 4; ++r) {
        rs[r] += __shfl_xor(rs[r], 1, 64);
        rs[r] += __shfl_xor(rs[r], 2, 64);
        rs[r] += __shfl_xor(rs[r], 4, 64);
        rs[r] += __shfl_xor(rs[r], 8, 64);
        lr[r] = lr[r] * al[r] + rs[r];
      }
#pragma unroll
      for (int d = 0; d < 8; ++d)
#pragma unroll
        for (int r = 0; r < 4; ++r) o[d][r] *= al[r];
      // P -> per-wave LDS (D-frag -> A-frag re-layout), then PV from swizzled Vs
#pragma unroll
      for (int jf = 0; jf < 4; ++jf)
#pragma unroll
        for (int r = 0; r < 4; ++r)
          P[w][g * 4 + r][jf * 16 + c] = (bf16_t)s[jf][r];
#pragma unroll
      for (int ks2 = 0; ks2 < 2; ++ks2) {
        const bf16x8 pa = *(const bf16x8*)&P[w][c][ks2 * 32 + g * 8];
#pragma unroll
        for (int d = 0; d < 8; ++d) {
          const bf16x8 vf = *(const bf16x8*)(Vc + (d * 16 + c) * 128 + (((ks2 * 4 + g) * 16) ^ sw));
          o[d] = __builtin_amdgcn_mfma_f32_16x16x32_bf16(pa, vf, o[d], 0, 0, 0);
        }
      }
      cur ^= 1;
    }

    float inv[4];
#pragma unroll
    for (int r = 0; r < 4; ++r) inv[r] = 1.0f / lr[r];
#pragma unroll
    for (int d = 0; d < 8; ++d)
#pragma unroll
      for (int r = 0; r < 4; ++r)
        Aout[(size_t)(b * T_ + q0 + w * 16 + g * 4 + r) * C_ + h * D_ + d * 16 + c] =
            (bf16_t)(o[d][r] * inv[r]);
  }
}

extern "C" void kernel_launch(void* const* d_in, const int* in_sizes, int n_in,
                              void* d_out, int out_size, void* d_ws, size_t ws_size,
                              hipStream_t stream) {
  const float* x  = (const float*)d_in[0];
  const float* Wq = (const float*)d_in[1];
  const float* bq = (const float*)d_in[2];
  const float* Wk = (const float*)d_in[3];
  const float* bk = (const float*)d_in[4];
  const float* Wv = (const float*)d_in[5];
  const float* bv = (const float*)d_in[6];
  const float* Wo = (const float*)d_in[7];
  const float* bo = (const float*)d_in[8];
  const float* qw = (const float*)d_in[9];
  const float* kw = (const float*)d_in[10];
  const float* fc = (const float*)d_in[11];
  const float* fs = (const float*)d_in[12];
  float* out = (float*)d_out;

  char* p = (char*)d_ws;
  bf16_t* xb   = (bf16_t*)p; p += (size_t)NT_ * C_ * 2;        // 16.8 MB (reused as attn out)
  bf16_t* Wqkv = (bf16_t*)p; p += (size_t)NQKV_ * C_ * 2;      // 12.6 MB  [N][K] bf16
  bf16_t* Wot  = (bf16_t*)p; p += (size_t)C_ * C_ * 2;         //  8.4 MB  [N][K] bf16
  float*  qkv  = (float*)p;  p += (size_t)NT_ * NQKV_ * 4;     // 50.3 MB
  bf16_t* Qb   = (bf16_t*)p; p += (size_t)B_ * H_ * T_ * D_ * 2;   // 16.8 MB
  bf16_t* Kb   = (bf16_t*)p; p += (size_t)B_ * KV_ * T_ * D_ * 2;  //  4.2 MB
  bf16_t* Vt   = (bf16_t*)p; p += (size_t)B_ * KV_ * T_ * D_ * 2;  //  4.2 MB [b][kv][d][T]
  float*  bqkv = (float*)p;  p += NQKV_ * 4;
  bf16_t* attn = xb;  // xb dead after GEMM1

  k_convert<<<NT_ * C_ / 4 / 256, 256, 0, stream>>>(x, xb, NT_ * C_ / 4);
  k_transpose<<<dim3(64, 64), 256, 0, stream>>>(Wq, Wqkv, 2048, 2048);
  k_transpose<<<dim3(16, 64), 256, 0, stream>>>(Wk, Wqkv + (size_t)2048 * 2048, 2048, 512);
  k_transpose<<<dim3(16, 64), 256, 0, stream>>>(Wv, Wqkv + (size_t)2560 * 2048, 2048, 512);
  k_transpose<<<dim3(64, 64), 256, 0, stream>>>(Wo, Wot, 2048, 2048);
  k_bias<<<12, 256, 0, stream>>>(bq, bk, bv, bqkv);
  k_gemm<<<dim3(NQKV_ / 128, NT_ / 256), 512, 0, stream>>>(xb, Wqkv, bqkv, qkv, NQKV_);
  k_rmsrope<<<dim3(NT_, 6), 256, 0, stream>>>(qkv, qw, kw, fc, fs, Qb, Kb, Vt);
  k_attn<<<dim3(16, H_, B_), 256, 0, stream>>>(Qb, Kb, Vt, attn);
  k_gemm<<<dim3(C_ / 128, NT_ / 256), 512, 0, stream>>>(attn, Wot, bo, out, C_);
}

// Round 5
// 363.688 us; speedup vs baseline: 2.1574x; 1.0584x over previous
//
#include <hip/hip_runtime.h>

typedef __bf16 bf16_t;
typedef __bf16 bf16x8 __attribute__((ext_vector_type(8)));
typedef __bf16 bf16x4 __attribute__((ext_vector_type(4)));
typedef float f32x4 __attribute__((ext_vector_type(4)));
typedef float f32x16 __attribute__((ext_vector_type(16)));
typedef unsigned int u32;

#define B_    2
#define T_    2048
#define C_    2048
#define H_    16
#define KV_   4
#define D_    128
#define NT_   4096   // B*T
#define NQKV_ 3072   // H*D + 2*KV*D

__device__ __forceinline__ void gload16(const void* g, void* l) {
  __builtin_amdgcn_global_load_lds((const __attribute__((address_space(1))) u32*)g,
                                   (__attribute__((address_space(3))) u32*)l, 16, 0, 0);
}

__device__ __forceinline__ u32 pack2(float lo, float hi) {
  return ((u32)__builtin_bit_cast(unsigned short, (bf16_t)hi) << 16) |
         (u32)__builtin_bit_cast(unsigned short, (bf16_t)lo);
}
// v_permlane32_swap_b32 vdst, vsrc: vdst.hi <-> vsrc.lo
__device__ __forceinline__ void plswap(u32& x, u32& y) {
  asm volatile("v_permlane32_swap_b32 %0, %1" : "+v"(x), "+v"(y));
}

// ---------------- fp32 -> bf16 convert (vectorized) ----------------
__global__ __launch_bounds__(256) void k_convert(const float* __restrict__ x,
                                                 bf16_t* __restrict__ y, int n4) {
  int i = blockIdx.x * 256 + threadIdx.x;
  if (i >= n4) return;
  float4 v = ((const float4*)x)[i];
  bf16x4 o;
  o[0] = (bf16_t)v.x; o[1] = (bf16_t)v.y; o[2] = (bf16_t)v.z; o[3] = (bf16_t)v.w;
  ((bf16x4*)y)[i] = o;
}

// ---------------- W[K][N] fp32 -> Wt[N][K] bf16 (LDS tile transpose) ----------------
__global__ __launch_bounds__(256) void k_transpose(const float* __restrict__ W,
                                                   bf16_t* __restrict__ Wt, int K, int N) {
  __shared__ float tile[32][33];
  int n0 = blockIdx.x * 32, k0 = blockIdx.y * 32;
  int tx = threadIdx.x & 31, ty = threadIdx.x >> 5;  // ty in 0..7
#pragma unroll
  for (int r = 0; r < 32; r += 8)
    tile[ty + r][tx] = W[(size_t)(k0 + ty + r) * N + n0 + tx];
  __syncthreads();
#pragma unroll
  for (int r = 0; r < 32; r += 8)
    Wt[(size_t)(n0 + ty + r) * K + k0 + tx] = (bf16_t)tile[tx][ty + r];
}

// ---------------- bias concat [bq|bk|bv] ----------------
__global__ void k_bias(const float* __restrict__ bq, const float* __restrict__ bk,
                       const float* __restrict__ bv, float* __restrict__ o) {
  int i = blockIdx.x * 256 + threadIdx.x;
  if (i < 2048) o[i] = bq[i];
  else if (i < 2560) o[i] = bk[i - 2048];
  else if (i < 3072) o[i] = bv[i - 2560];
}

// ---------------- GEMM v2: phase-pipelined 256x128 tile ----------------
__global__ __launch_bounds__(512, 2) void k_gemm(const bf16_t* __restrict__ A,
                                                 const bf16_t* __restrict__ Wt,
                                                 const float* __restrict__ bias,
                                                 float* __restrict__ Cout, int NTOT) {
  constexpr int K = 2048;
  constexpr int NK = K / 64;             // 32 K-tiles
  __shared__ __align__(16) bf16_t Asr[3][256 * 64];   // 96 KB
  __shared__ __align__(16) bf16_t Bsr[3][128 * 64];   // 48 KB
  const int tid = threadIdx.x;
  const int lane = tid & 63, w = tid >> 6;
  const int c = lane & 15, g = lane >> 4;
  const int wr = w >> 1, wc = w & 1;
  const int m0 = blockIdx.y * 256, n0 = blockIdx.x * 128;

  int arow[4], asc[4], brow[2], bsc[2];
#pragma unroll
  for (int i = 0; i < 4; ++i) {
    const int ck = i * 512 + w * 64 + lane;
    arow[i] = ck >> 3; asc[i] = ((ck & 7) ^ ((ck >> 3) & 7)) * 8;
  }
#pragma unroll
  for (int j = 0; j < 2; ++j) {
    const int ck = j * 512 + w * 64 + lane;
    brow[j] = ck >> 3; bsc[j] = ((ck & 7) ^ ((ck >> 3) & 7)) * 8;
  }
  const int swz0 = ((0 * 4 + g) ^ (c & 7)) * 8;
  const int swz1 = ((1 * 4 + g) ^ (c & 7)) * 8;
  const int aro = (wr * 64 + c) * 64;    // + m*1024
  const int bro = (wc * 64 + c) * 64;    // + n*1024

  const f32x4 fz = {0.f, 0.f, 0.f, 0.f};
  f32x4 acc[4][4];
#pragma unroll
  for (int m = 0; m < 4; ++m)
#pragma unroll
    for (int n = 0; n < 4; ++n) acc[m][n] = fz;

  auto stageA2 = [&](int ts, int sl, int i0) {
    const int k0 = ts * 64;
#pragma unroll
    for (int i = i0; i < i0 + 2; ++i)
      gload16(A + (size_t)(m0 + arow[i]) * K + k0 + asc[i],
              Asr[sl] + (i * 512 + w * 64) * 8);
  };
  auto stageB1 = [&](int ts, int sl, int j) {
    const int k0 = ts * 64;
    gload16(Wt + (size_t)(n0 + brow[j]) * K + k0 + bsc[j],
            Bsr[sl] + (j * 512 + w * 64) * 8);
  };

  stageA2(0, 0, 0); stageA2(0, 0, 2); stageB1(0, 0, 0); stageB1(0, 0, 1);
  stageA2(1, 1, 0); stageA2(1, 1, 2); stageB1(1, 1, 0); stageB1(1, 1, 1);
  asm volatile("s_waitcnt vmcnt(6)" ::: "memory");
  __builtin_amdgcn_s_barrier();

  int slot = 0;
#pragma unroll 1
  for (int t = 0; t < NK; ++t) {
    const int sl2 = (slot >= 1) ? slot - 1 : 2;          // (t+2) % 3
    const int ts = (t + 2 < NK) ? t + 2 : NK - 1;        // clamp: garbage into dead slot
    const bf16_t* Ap = Asr[slot];
    const bf16_t* Bp = Bsr[slot];

    bf16x8 af[4][2], b01[2][2];
#pragma unroll
    for (int m = 0; m < 4; ++m) {
      af[m][0] = *(const bf16x8*)(Ap + aro + m * 1024 + swz0);
      af[m][1] = *(const bf16x8*)(Ap + aro + m * 1024 + swz1);
    }
#pragma unroll
    for (int n = 0; n < 2; ++n) {
      b01[n][0] = *(const bf16x8*)(Bp + bro + n * 1024 + swz0);
      b01[n][1] = *(const bf16x8*)(Bp + bro + n * 1024 + swz1);
    }
    stageA2(ts, sl2, 0); stageB1(ts, sl2, 0);
    __builtin_amdgcn_s_barrier();
    asm volatile("s_waitcnt lgkmcnt(0)" ::: "memory");
    __builtin_amdgcn_sched_barrier(0);
    __builtin_amdgcn_s_setprio(1);
#pragma unroll
    for (int m = 0; m < 4; ++m)
#pragma unroll
      for (int n = 0; n < 2; ++n) {
        acc[m][n] = __builtin_amdgcn_mfma_f32_16x16x32_bf16(af[m][0], b01[n][0], acc[m][n], 0, 0, 0);
        acc[m][n] = __builtin_amdgcn_mfma_f32_16x16x32_bf16(af[m][1], b01[n][1], acc[m][n], 0, 0, 0);
      }
    __builtin_amdgcn_s_setprio(0);
    __builtin_amdgcn_s_barrier();

    bf16x8 b23[2][2];
#pragma unroll
    for (int n = 0; n < 2; ++n) {
      b23[n][0] = *(const bf16x8*)(Bp + bro + (n + 2) * 1024 + swz0);
      b23[n][1] = *(const bf16x8*)(Bp + bro + (n + 2) * 1024 + swz1);
    }
    stageA2(ts, sl2, 2); stageB1(ts, sl2, 1);
    __builtin_amdgcn_s_barrier();
    asm volatile("s_waitcnt lgkmcnt(0)" ::: "memory");
    __builtin_amdgcn_sched_barrier(0);
    __builtin_amdgcn_s_setprio(1);
#pragma unroll
    for (int m = 0; m < 4; ++m)
#pragma unroll
      for (int n = 0; n < 2; ++n) {
        acc[m][n + 2] = __builtin_amdgcn_mfma_f32_16x16x32_bf16(af[m][0], b23[n][0], acc[m][n + 2], 0, 0, 0);
        acc[m][n + 2] = __builtin_amdgcn_mfma_f32_16x16x32_bf16(af[m][1], b23[n][1], acc[m][n + 2], 0, 0, 0);
      }
    __builtin_amdgcn_s_setprio(0);
    asm volatile("s_waitcnt vmcnt(6)" ::: "memory");   // tile t+1 fully landed
    __builtin_amdgcn_s_barrier();
    __builtin_amdgcn_sched_barrier(0);
    slot = (slot == 2) ? 0 : slot + 1;
  }

#pragma unroll
  for (int n = 0; n < 4; ++n) {
    const int col = n0 + wc * 64 + n * 16 + c;
    const float bn = bias[col];
#pragma unroll
    for (int m = 0; m < 4; ++m) {
      const int row = m0 + wr * 64 + m * 16 + g * 4;
#pragma unroll
      for (int r = 0; r < 4; ++r)
        Cout[(size_t)(row + r) * NTOT + col] = acc[m][n][r] + bn;
    }
  }
}

// ---------------- RMSNorm + RoPE (Q pre-scaled by 1/sqrt(D)*log2e) ----------------
__global__ __launch_bounds__(256) void k_rmsrope(const float* __restrict__ qkv,
                                                 const float* __restrict__ qw,
                                                 const float* __restrict__ kw,
                                                 const float* __restrict__ fc,
                                                 const float* __restrict__ fs,
                                                 bf16_t* __restrict__ Qb,
                                                 bf16_t* __restrict__ Kb,
                                                 bf16_t* __restrict__ Vt) {
  const int bt = blockIdx.x;
  const int u = blockIdx.y * 4 + (threadIdx.x >> 6);  // 0..23
  const int lane = threadIdx.x & 63;
  const int b = bt >> 11, t = bt & (T_ - 1);
  int off;
  if (u < 16) off = u * 128;
  else if (u < 20) off = 2048 + (u - 16) * 128;
  else off = 2560 + (u - 20) * 128;
  const float2 ab = *(const float2*)(qkv + (size_t)bt * NQKV_ + off + 2 * lane);
  const float a = ab.x, bv_ = ab.y;
  if (u < 20) {
    float ssq = a * a + bv_ * bv_;
#pragma unroll
    for (int o = 32; o; o >>= 1) ssq += __shfl_xor(ssq, o, 64);
    const float r = rsqrtf(ssq * (1.0f / 128.0f) + 1e-5f);
    const float* wgt = (u < 16) ? qw : kw;
    const float a2 = a * r * wgt[2 * lane];
    const float b2 = bv_ * r * wgt[2 * lane + 1];
    const float cs = fc[t * 64 + lane], sn = fs[t * 64 + lane];
    float o0 = a2 * cs - b2 * sn;
    float o1 = a2 * sn + b2 * cs;
    if (u < 16) {  // fold softmax scale + log2(e) into Q
      const float SCLQ = 0.08838834764831845f * 1.4426950408889634f;
      o0 *= SCLQ; o1 *= SCLQ;
    }
    const u32 pk = ((u32)__builtin_bit_cast(unsigned short, (bf16_t)o1) << 16) |
                   (u32)__builtin_bit_cast(unsigned short, (bf16_t)o0);
    if (u < 16)
      *(u32*)(Qb + ((size_t)(b * H_ + u) * T_ + t) * D_ + 2 * lane) = pk;
    else
      *(u32*)(Kb + ((size_t)(b * KV_ + (u - 16)) * T_ + t) * D_ + 2 * lane) = pk;
  } else {
    const int kv = u - 20;
    bf16_t* vp = Vt + (size_t)(b * KV_ + kv) * D_ * T_;
    vp[(size_t)(2 * lane) * T_ + t] = (bf16_t)a;
    vp[(size_t)(2 * lane + 1) * T_ + t] = (bf16_t)bv_;
  }
}

// ---------------- causal GQA flash attention v4: swapped 32x32 MFMA ----------------
// 256 blocks (1/CU, XCD-colocated per (b,kv)) x 8 waves = 4 q-waves x 2 key-split.
// q-tile 128, KVBLK 64, qt-pairing (pi,15-pi) -> 34 balanced units/block.
// S^T = mfma(K,Q): lane owns one q-row -> softmax nearly lane-local.
// O^T += mfma(V^T, P^T): P^T B-frag built in-register via pack + permlane32_swap.
// Key-split halves merged (m,l,O) once per q-tile through LDS scratch.
__global__ __launch_bounds__(512, 2) void k_attn(const bf16_t* __restrict__ Q,
                                                 const bf16_t* __restrict__ K,
                                                 const bf16_t* __restrict__ Vt,
                                                 bf16_t* __restrict__ Aout) {
  const int wg = blockIdx.x;
  const int xcd = wg & 7, idx = wg >> 3;
  const int b = xcd >> 2, kvh = xcd & 3;
  const int h = kvh * 4 + (idx & 3);
  const int pi = idx >> 2;  // 0..7 -> q-tile pair (pi, 15-pi)

  const int tid = threadIdx.x, lane = tid & 63, w = tid >> 6;
  const int c5 = lane & 31, g = lane >> 5;
  const int wq = w >> 1, wk = w & 1;

  __shared__ __align__(16) bf16_t Ks[2][64 * 128];  // [key][d], 256B rows, chunk^=row&15
  __shared__ __align__(16) bf16_t Vs[2][128 * 64];  // [d][key], 128B rows, chunk^=row&7
  __shared__ float Os[4][64][64];                   // merge scratch (64 KB)
  __shared__ float Ms[4][64], Ls[4][64];

  const bf16_t* Kp = K + (size_t)(b * KV_ + kvh) * T_ * D_;
  const bf16_t* Vp = Vt + (size_t)(b * KV_ + kvh) * D_ * T_;

  int kr[2], kc[2], vr[2], vc[2];
#pragma unroll
  for (int i = 0; i < 2; ++i) {
    const int ck = i * 512 + tid;
    kr[i] = ck >> 4; kc[i] = ((ck & 15) ^ (kr[i] & 15)) * 8;
    vr[i] = ck >> 3; vc[i] = ((ck & 7) ^ (vr[i] & 7)) * 8;
  }
  auto stage = [&](int k0, int buf) {
#pragma unroll
    for (int i = 0; i < 2; ++i) {
      gload16(Kp + (size_t)(k0 + kr[i]) * D_ + kc[i], Ks[buf] + (i * 512 + w * 64) * 8);
      gload16(Vp + (size_t)vr[i] * T_ + k0 + vc[i], Vs[buf] + (i * 512 + w * 64) * 8);
    }
  };

#pragma unroll 1
  for (int ph = 0; ph < 2; ++ph) {
    const int qt = ph ? 15 - pi : pi;
    const int q0 = qt * 128;
    const int nkt = 2 * (qt + 1);
    const int qrow = q0 + wq * 32 + c5;  // lane's q-row (softmax state domain)
    const bf16_t* Qp = Q + ((size_t)(b * H_ + h) * T_ + qrow) * D_;
    bf16x8 qf[8];
#pragma unroll
    for (int t = 0; t < 8; ++t) qf[t] = *(const bf16x8*)(Qp + t * 16 + g * 8);

    f32x16 o[4];
#pragma unroll
    for (int d = 0; d < 4; ++d)
#pragma unroll
      for (int r = 0; r < 16; ++r) o[d][r] = 0.f;
    float mr = 0.f, lr = 0.f;  // m floor 0 avoids -inf NaN on masked tiles

    if (ph == 1) __syncthreads();  // all waves done with previous phase LDS
    stage(0, 0);
    int cur = 0;

#pragma unroll 1
    for (int kt = 0; kt < nkt; ++kt) {
      __syncthreads();  // staged buf[cur] ready (vmcnt drained); buf[cur^1] free
      if (kt + 1 < nkt) stage((kt + 1) * 64, cur ^ 1);
      const int kbase = kt * 64 + wk * 32;  // this wave's 32-key half
      if (kbase <= q0 + wq * 32 + 31) {     // skip fully-masked sub-tiles
        const bf16_t* Kc = Ks[cur];
        const bf16_t* Vc = Vs[cur];
        const int sw16 = c5 & 15, sw8 = c5 & 7;
        const int krowoff = (wk * 32 + c5) * 128;

        // S^T = K . Q^T  (lane: q = c5, keys (r&3)+8*(r>>2)+4g)
        f32x16 s;
#pragma unroll
        for (int r = 0; r < 16; ++r) s[r] = 0.f;
#pragma unroll
        for (int t = 0; t < 8; ++t) {
          bf16x8 kf = *(const bf16x8*)(Kc + krowoff + (((2 * t + g) ^ sw16) * 8));
          s = __builtin_amdgcn_mfma_f32_32x32x16_bf16(kf, qf[t], s, 0, 0, 0);
        }
        if (kbase + 31 > q0 + wq * 32) {  // diagonal region: causal mask
#pragma unroll
          for (int r = 0; r < 16; ++r) {
            const int key = kbase + (r & 3) + 8 * (r >> 2) + 4 * g;
            s[r] = (key <= qrow) ? s[r] : -1e30f;
          }
        }
        // online softmax (scaled-by-log2e domain; per-lane scalar state)
        float tm = s[0];
#pragma unroll
        for (int r = 1; r < 16; ++r) tm = fmaxf(tm, s[r]);
        tm = fmaxf(tm, __shfl_xor(tm, 32, 64));
        const float nm = fmaxf(mr, tm);
        const float al = exp2f(mr - nm);
        mr = nm;
        float p[16];
        float rs = 0.f;
#pragma unroll
        for (int r = 0; r < 16; ++r) { p[r] = exp2f(s[r] - nm); rs += p[r]; }
        rs += __shfl_xor(rs, 32, 64);
        lr = lr * al + rs;
#pragma unroll
        for (int d = 0; d < 4; ++d)
#pragma unroll
          for (int r = 0; r < 16; ++r) o[d][r] *= al;

        // P^T B-frags: pack pairs, permlane32_swap exchanges half-wave halves
        u32 pk01[4], pk23[4];
#pragma unroll
        for (int b2 = 0; b2 < 4; ++b2) {
          pk01[b2] = pack2(p[4 * b2], p[4 * b2 + 1]);
          pk23[b2] = pack2(p[4 * b2 + 2], p[4 * b2 + 3]);
        }
#pragma unroll
        for (int i = 0; i < 2; ++i) {
          u32 a0 = pk01[2 * i], b0 = pk01[2 * i + 1];
          u32 a1 = pk23[2 * i], b1 = pk23[2 * i + 1];
          plswap(a0, b0); plswap(a1, b1);
          union { u32 u[4]; bf16x8 v; } pu;
          pu.u[0] = a0; pu.u[1] = a1; pu.u[2] = b0; pu.u[3] = b1;
#pragma unroll
          for (int d = 0; d < 4; ++d) {
            bf16x8 vf = *(const bf16x8*)(Vc + (d * 32 + c5) * 64 +
                                         (((wk * 4 + 2 * i + g) ^ sw8) * 8));
            o[d] = __builtin_amdgcn_mfma_f32_32x32x16_bf16(vf, pu.v, o[d], 0, 0, 0);
          }
        }
      }
      cur ^= 1;
    }

    // merge key-split halves: wk=1 -> LDS -> wk=0 combines + writes
    if (wk == 1) {
#pragma unroll
      for (int d = 0; d < 4; ++d)
#pragma unroll
        for (int r = 0; r < 16; ++r) Os[wq][d * 16 + r][lane] = o[d][r];
      Ms[wq][lane] = mr; Ls[wq][lane] = lr;
    }
    __syncthreads();
    if (wk == 0) {
      const float m1 = Ms[wq][lane], l1 = Ls[wq][lane];
      const float nm = fmaxf(mr, m1);
      const float a0 = exp2f(mr - nm), a1 = exp2f(m1 - nm);
      const float inv = 1.0f / (lr * a0 + l1 * a1);
      bf16_t* op = Aout + (size_t)(b * T_ + qrow) * C_ + h * D_;
#pragma unroll
      for (int d = 0; d < 4; ++d)
#pragma unroll
        for (int b2 = 0; b2 < 4; ++b2) {
          bf16x4 pkv;
#pragma unroll
          for (int r3 = 0; r3 < 4; ++r3)
            pkv[r3] = (bf16_t)((o[d][4 * b2 + r3] * a0 +
                                Os[wq][d * 16 + 4 * b2 + r3][lane] * a1) * inv);
          *(bf16x4*)(op + d * 32 + 8 * b2 + 4 * g) = pkv;
        }
    }
  }
}

extern "C" void kernel_launch(void* const* d_in, const int* in_sizes, int n_in,
                              void* d_out, int out_size, void* d_ws, size_t ws_size,
                              hipStream_t stream) {
  const float* x  = (const float*)d_in[0];
  const float* Wq = (const float*)d_in[1];
  const float* bq = (const float*)d_in[2];
  const float* Wk = (const float*)d_in[3];
  const float* bk = (const float*)d_in[4];
  const float* Wv = (const float*)d_in[5];
  const float* bv = (const float*)d_in[6];
  const float* Wo = (const float*)d_in[7];
  const float* bo = (const float*)d_in[8];
  const float* qw = (const float*)d_in[9];
  const float* kw = (const float*)d_in[10];
  const float* fc = (const float*)d_in[11];
  const float* fs = (const float*)d_in[12];
  float* out = (float*)d_out;

  char* p = (char*)d_ws;
  bf16_t* xb   = (bf16_t*)p; p += (size_t)NT_ * C_ * 2;        // 16.8 MB (reused as attn out)
  bf16_t* Wqkv = (bf16_t*)p; p += (size_t)NQKV_ * C_ * 2;      // 12.6 MB  [N][K] bf16
  bf16_t* Wot  = (bf16_t*)p; p += (size_t)C_ * C_ * 2;         //  8.4 MB  [N][K] bf16
  float*  qkv  = (float*)p;  p += (size_t)NT_ * NQKV_ * 4;     // 50.3 MB
  bf16_t* Qb   = (bf16_t*)p; p += (size_t)B_ * H_ * T_ * D_ * 2;   // 16.8 MB
  bf16_t* Kb   = (bf16_t*)p; p += (size_t)B_ * KV_ * T_ * D_ * 2;  //  4.2 MB
  bf16_t* Vt   = (bf16_t*)p; p += (size_t)B_ * KV_ * T_ * D_ * 2;  //  4.2 MB [b][kv][d][T]
  float*  bqkv = (float*)p;  p += NQKV_ * 4;
  bf16_t* attn = xb;  // xb dead after GEMM1

  k_convert<<<NT_ * C_ / 4 / 256, 256, 0, stream>>>(x, xb, NT_ * C_ / 4);
  k_transpose<<<dim3(64, 64), 256, 0, stream>>>(Wq, Wqkv, 2048, 2048);
  k_transpose<<<dim3(16, 64), 256, 0, stream>>>(Wk, Wqkv + (size_t)2048 * 2048, 2048, 512);
  k_transpose<<<dim3(16, 64), 256, 0, stream>>>(Wv, Wqkv + (size_t)2560 * 2048, 2048, 512);
  k_transpose<<<dim3(64, 64), 256, 0, stream>>>(Wo, Wot, 2048, 2048);
  k_bias<<<12, 256, 0, stream>>>(bq, bk, bv, bqkv);
  k_gemm<<<dim3(NQKV_ / 128, NT_ / 256), 512, 0, stream>>>(xb, Wqkv, bqkv, qkv, NQKV_);
  k_rmsrope<<<dim3(NT_, 6), 256, 0, stream>>>(qkv, qw, kw, fc, fs, Qb, Kb, Vt);
  k_attn<<<256, 512, 0, stream>>>(Qb, Kb, Vt, attn);
  k_gemm<<<dim3(C_ / 128, NT_ / 256), 512, 0, stream>>>(attn, Wot, bo, out, C_);
}